// Round 1
// baseline (2728.778 us; speedup 1.0000x reference)
//
#include <hip/hip_runtime.h>
#include <hip/hip_bf16.h>
#include <math.h>

#define S_LEN 2048
#define HID   1024
#define INNER 2048
#define NCONV 4
#define LSTATE 16
#define DRANK 64
#define XPW   96   // DRANK + 2*LSTATE

// ---------------- generic tiled fp32 GEMM: C = A[M,K] @ B[K,N] --------------
// EPI: 0 = plain store, 1 = softplus(acc + bias) store
template<int EPI>
__global__ __launch_bounds__(256) void gemm_tiled(
    const float* __restrict__ A, int lda,
    const float* __restrict__ B, int ldb,
    float* __restrict__ C, int ldc,
    int M, int N, int K, const float* __restrict__ bias) {
  __shared__ float As[16][65];   // As[k][m], padded
  __shared__ float Bs[16][65];   // Bs[k][n], padded
  const int bm = blockIdx.y * 64;
  const int bn = blockIdx.x * 64;
  const int tid = threadIdx.x;
  const int tx = tid & 15;       // 16 col groups of 4
  const int ty = tid >> 4;       // 16 row groups of 4
  float acc[4][4] = {};
  for (int k0 = 0; k0 < K; k0 += 16) {
    #pragma unroll
    for (int i = tid; i < 64 * 16; i += 256) {
      int m = i >> 4, kk = i & 15;
      As[kk][m] = A[(size_t)(bm + m) * lda + k0 + kk];
    }
    #pragma unroll
    for (int i = tid; i < 16 * 64; i += 256) {
      int kk = i >> 6, n = i & 63;
      Bs[kk][n] = B[(size_t)(k0 + kk) * ldb + bn + n];
    }
    __syncthreads();
    #pragma unroll
    for (int kk = 0; kk < 16; ++kk) {
      float a[4], b[4];
      #pragma unroll
      for (int i = 0; i < 4; ++i) a[i] = As[kk][ty * 4 + i];
      #pragma unroll
      for (int j = 0; j < 4; ++j) b[j] = Bs[kk][tx * 4 + j];
      #pragma unroll
      for (int i = 0; i < 4; ++i)
        #pragma unroll
        for (int j = 0; j < 4; ++j)
          acc[i][j] += a[i] * b[j];
    }
    __syncthreads();
  }
  #pragma unroll
  for (int i = 0; i < 4; ++i) {
    #pragma unroll
    for (int j = 0; j < 4; ++j) {
      int row = bm + ty * 4 + i;
      int col = bn + tx * 4 + j;
      float v = acc[i][j];
      if (EPI == 1) {
        v += bias[col];
        // jax.nn.softplus == logaddexp(x, 0) == max(x,0) + log1p(exp(-|x|))
        v = fmaxf(v, 0.f) + log1pf(expf(-fabsf(v)));
      }
      C[(size_t)row * ldc + col] = v;
    }
  }
}

// ------------- depthwise causal conv (width 4) + bias + SiLU ----------------
__global__ __launch_bounds__(256) void conv_silu_kernel(
    const float* __restrict__ xz,   // [S, 2*INNER], xi = cols [0,INNER)
    const float* __restrict__ cw,   // [4,1,INNER]
    const float* __restrict__ cb,   // [INNER]
    float* __restrict__ xc) {       // [S, INNER]
  int idx = blockIdx.x * 256 + threadIdx.x;
  if (idx >= S_LEN * INNER) return;
  int s = idx / INNER;
  int c = idx - s * INNER;
  float acc = cb[c];
  #pragma unroll
  for (int k = 0; k < NCONV; ++k) {
    int t = s - (NCONV - 1) + k;
    if (t >= 0) acc += xz[(size_t)t * (2 * INNER) + c] * cw[k * INNER + c];
  }
  xc[idx] = acc / (1.f + expf(-acc));   // silu
}

// ------------------ xp = xc[S,INNER] @ W_x[INNER,96] ------------------------
__global__ __launch_bounds__(256) void gemm_xp_kernel(
    const float* __restrict__ xc, const float* __restrict__ Wx,
    float* __restrict__ xp) {
  __shared__ float As[16][33];    // [m][k]
  __shared__ float Bs[32][97];    // [k][n]
  const int bm = blockIdx.x * 16;
  const int tid = threadIdx.x;
  const int tx = tid & 15;        // 16 col groups of 6
  const int ty = tid >> 4;        // 16 rows
  float acc[6] = {};
  for (int k0 = 0; k0 < INNER; k0 += 32) {
    #pragma unroll
    for (int i = tid; i < 16 * 32; i += 256) {
      int m = i >> 5, kk = i & 31;
      As[m][kk] = xc[(size_t)(bm + m) * INNER + k0 + kk];
    }
    #pragma unroll
    for (int i = tid; i < 32 * 96; i += 256) {
      int kk = i / 96, n = i - kk * 96;
      Bs[kk][n] = Wx[(size_t)(k0 + kk) * XPW + n];
    }
    __syncthreads();
    #pragma unroll
    for (int kk = 0; kk < 32; ++kk) {
      float a = As[ty][kk];
      #pragma unroll
      for (int j = 0; j < 6; ++j) acc[j] += a * Bs[kk][tx * 6 + j];
    }
    __syncthreads();
  }
  #pragma unroll
  for (int j = 0; j < 6; ++j)
    xp[(size_t)(bm + ty) * XPW + tx * 6 + j] = acc[j];
}

// --------------------------- sequential SSM scan ----------------------------
// one thread per (d, l) chain; 16 consecutive lanes = one d's 16 l-states
__global__ __launch_bounds__(256) void scan_kernel(
    const float* __restrict__ delta,  // [S, INNER]
    const float* __restrict__ xp,     // [S, 96]; B at col 64, C at col 80
    const float* __restrict__ xc,     // [S, INNER]
    const float* __restrict__ xz,     // [S, 2*INNER]; z = cols [INNER, 2*INNER)
    const float* __restrict__ A_log,  // [INNER, L]
    const float* __restrict__ Dvec,   // [INNER]
    float* __restrict__ y) {          // [S, INNER]
  const int tid = threadIdx.x;
  const int l = tid & 15;
  const int dloc = tid >> 4;
  const int d = blockIdx.x * 16 + dloc;
  const float a = -expf(A_log[d * LSTATE + l]);
  const float Dd = Dvec[d];
  float h = 0.f;
  for (int s = 0; s < S_LEN; ++s) {
    float dv  = delta[(size_t)s * INNER + d];
    float xcv = xc[(size_t)s * INNER + d];
    float bm  = xp[(size_t)s * XPW + DRANK + l];
    float cm  = xp[(size_t)s * XPW + DRANK + LSTATE + l];
    float dA  = expf(dv * a);
    h = dA * h + dv * bm * xcv;
    float contrib = h * cm;
    contrib += __shfl_xor(contrib, 1);
    contrib += __shfl_xor(contrib, 2);
    contrib += __shfl_xor(contrib, 4);
    contrib += __shfl_xor(contrib, 8);
    if (l == 0) {
      float zv = xz[(size_t)s * (2 * INNER) + INNER + d];
      float silu_z = zv / (1.f + expf(-zv));
      y[(size_t)s * INNER + d] = (contrib + xcv * Dd) * silu_z;
    }
  }
}

extern "C" void kernel_launch(void* const* d_in, const int* in_sizes, int n_in,
                              void* d_out, int out_size, void* d_ws, size_t ws_size,
                              hipStream_t stream) {
  const float* x      = (const float*)d_in[0];   // [S, HID]
  const float* W_in   = (const float*)d_in[1];   // [HID, 2*INNER]
  const float* conv_w = (const float*)d_in[2];   // [4,1,INNER]
  const float* conv_b = (const float*)d_in[3];   // [INNER]
  const float* W_x    = (const float*)d_in[4];   // [INNER, 96]
  const float* W_delta= (const float*)d_in[5];   // [DRANK, INNER]
  const float* b_delta= (const float*)d_in[6];   // [INNER]
  const float* A_log  = (const float*)d_in[7];   // [INNER, L]
  const float* Dvec   = (const float*)d_in[8];   // [INNER]
  const float* W_out  = (const float*)d_in[9];   // [INNER, HID]
  float* out = (float*)d_out;

  float* ws    = (float*)d_ws;
  float* xz    = ws;                               // S * 2*INNER  = 8,388,608
  float* xc    = xz + (size_t)S_LEN * 2 * INNER;   // S * INNER    = 4,194,304
  float* xp    = xc + (size_t)S_LEN * INNER;       // S * 96       =   196,608
  float* delta = xp + (size_t)S_LEN * XPW;         // S * INNER    = 4,194,304
  float* y     = delta + (size_t)S_LEN * INNER;    // S * INNER    = 4,194,304

  // 1. xz = x @ W_in   (M=2048, N=4096, K=1024)
  gemm_tiled<0><<<dim3(4096 / 64, 2048 / 64), 256, 0, stream>>>(
      x, HID, W_in, 2 * INNER, xz, 2 * INNER, S_LEN, 2 * INNER, HID, nullptr);

  // 2. xc = silu(causal_depthwise_conv(xi) + conv_b)
  conv_silu_kernel<<<(S_LEN * INNER + 255) / 256, 256, 0, stream>>>(
      xz, conv_w, conv_b, xc);

  // 3. xp = xc @ W_x   (M=2048, N=96, K=2048)
  gemm_xp_kernel<<<S_LEN / 16, 256, 0, stream>>>(xc, W_x, xp);

  // 4. delta = softplus(xp[:, :64] @ W_delta + b_delta)  (M=2048, N=2048, K=64)
  gemm_tiled<1><<<dim3(2048 / 64, 2048 / 64), 256, 0, stream>>>(
      xp, XPW, W_delta, INNER, delta, INNER, S_LEN, INNER, DRANK, b_delta);

  // 5. SSM scan -> y (fused with +xc*D and *silu(z))
  scan_kernel<<<INNER / 16, 256, 0, stream>>>(
      delta, xp, xc, xz, A_log, Dvec, y);

  // 6. out = y @ W_out  (M=2048, N=1024, K=2048)
  gemm_tiled<0><<<dim3(1024 / 64, 2048 / 64), 256, 0, stream>>>(
      y, INNER, W_out, HID, out, HID, S_LEN, HID, INNER, nullptr);
}

// Round 2
// 1222.111 us; speedup vs baseline: 2.2328x; 2.2328x over previous
//
#include <hip/hip_runtime.h>
#include <hip/hip_bf16.h>
#include <math.h>

#define S_LEN 2048
#define HID   1024
#define INNER 2048
#define NCONV 4
#define LSTATE 16
#define DRANK 64
#define XPW   96   // DRANK + 2*LSTATE
#define CHUNK 32
#define NCHUNK (S_LEN / CHUNK)   // 64

// ---------------- generic tiled fp32 GEMM: C = A[M,K] @ B[K,N] --------------
// EPI: 0 = plain store, 1 = softplus(acc + bias) store
template<int EPI>
__global__ __launch_bounds__(256) void gemm_tiled(
    const float* __restrict__ A, int lda,
    const float* __restrict__ B, int ldb,
    float* __restrict__ C, int ldc,
    int M, int N, int K, const float* __restrict__ bias) {
  __shared__ float As[16][65];   // As[k][m], padded
  __shared__ float Bs[16][65];   // Bs[k][n], padded
  const int bm = blockIdx.y * 64;
  const int bn = blockIdx.x * 64;
  const int tid = threadIdx.x;
  const int tx = tid & 15;       // 16 col groups of 4
  const int ty = tid >> 4;       // 16 row groups of 4
  float acc[4][4] = {};
  for (int k0 = 0; k0 < K; k0 += 16) {
    #pragma unroll
    for (int i = tid; i < 64 * 16; i += 256) {
      int m = i >> 4, kk = i & 15;
      As[kk][m] = A[(size_t)(bm + m) * lda + k0 + kk];
    }
    #pragma unroll
    for (int i = tid; i < 16 * 64; i += 256) {
      int kk = i >> 6, n = i & 63;
      Bs[kk][n] = B[(size_t)(k0 + kk) * ldb + bn + n];
    }
    __syncthreads();
    #pragma unroll
    for (int kk = 0; kk < 16; ++kk) {
      float a[4], b[4];
      #pragma unroll
      for (int i = 0; i < 4; ++i) a[i] = As[kk][ty * 4 + i];
      #pragma unroll
      for (int j = 0; j < 4; ++j) b[j] = Bs[kk][tx * 4 + j];
      #pragma unroll
      for (int i = 0; i < 4; ++i)
        #pragma unroll
        for (int j = 0; j < 4; ++j)
          acc[i][j] += a[i] * b[j];
    }
    __syncthreads();
  }
  #pragma unroll
  for (int i = 0; i < 4; ++i) {
    #pragma unroll
    for (int j = 0; j < 4; ++j) {
      int row = bm + ty * 4 + i;
      int col = bn + tx * 4 + j;
      float v = acc[i][j];
      if (EPI == 1) {
        v += bias[col];
        // jax.nn.softplus == max(x,0) + log1p(exp(-|x|))
        v = fmaxf(v, 0.f) + log1pf(expf(-fabsf(v)));
      }
      C[(size_t)row * ldc + col] = v;
    }
  }
}

// ------------- depthwise causal conv (width 4) + bias + SiLU ----------------
__global__ __launch_bounds__(256) void conv_silu_kernel(
    const float* __restrict__ xz,   // [S, 2*INNER], xi = cols [0,INNER)
    const float* __restrict__ cw,   // [4,1,INNER]
    const float* __restrict__ cb,   // [INNER]
    float* __restrict__ xc) {       // [S, INNER]
  int idx = blockIdx.x * 256 + threadIdx.x;
  if (idx >= S_LEN * INNER) return;
  int s = idx / INNER;
  int c = idx - s * INNER;
  float acc = cb[c];
  #pragma unroll
  for (int k = 0; k < NCONV; ++k) {
    int t = s - (NCONV - 1) + k;
    if (t >= 0) acc += xz[(size_t)t * (2 * INNER) + c] * cw[k * INNER + c];
  }
  xc[idx] = acc / (1.f + expf(-acc));   // silu
}

// ------------------ xp = xc[S,INNER] @ W_x[INNER,96] ------------------------
__global__ __launch_bounds__(256) void gemm_xp_kernel(
    const float* __restrict__ xc, const float* __restrict__ Wx,
    float* __restrict__ xp) {
  __shared__ float As[16][33];    // [m][k]
  __shared__ float Bs[32][97];    // [k][n]
  const int bm = blockIdx.x * 16;
  const int tid = threadIdx.x;
  const int tx = tid & 15;        // 16 col groups of 6
  const int ty = tid >> 4;        // 16 rows
  float acc[6] = {};
  for (int k0 = 0; k0 < INNER; k0 += 32) {
    #pragma unroll
    for (int i = tid; i < 16 * 32; i += 256) {
      int m = i >> 5, kk = i & 31;
      As[m][kk] = xc[(size_t)(bm + m) * INNER + k0 + kk];
    }
    #pragma unroll
    for (int i = tid; i < 32 * 96; i += 256) {
      int kk = i / 96, n = i - kk * 96;
      Bs[kk][n] = Wx[(size_t)(k0 + kk) * XPW + n];
    }
    __syncthreads();
    #pragma unroll
    for (int kk = 0; kk < 32; ++kk) {
      float a = As[ty][kk];
      #pragma unroll
      for (int j = 0; j < 6; ++j) acc[j] += a * Bs[kk][tx * 6 + j];
    }
    __syncthreads();
  }
  #pragma unroll
  for (int j = 0; j < 6; ++j)
    xp[(size_t)(bm + ty) * XPW + tx * 6 + j] = acc[j];
}

// ---------------- chunk-parallel SSM scan (3 passes) ------------------------
// Recurrence h[s] = dA[s]*h[s-1] + dBx[s] is a linear first-order recurrence;
// chunk it: pass1 local (Aprod, Hend) per chunk, pass2 compose carries,
// pass3 replay from carry-in with fused epilogue.

__global__ __launch_bounds__(256) void scan_pass1(
    const float* __restrict__ delta,  // [S, INNER]
    const float* __restrict__ xp,     // [S, 96]
    const float* __restrict__ xc,     // [S, INNER]
    const float* __restrict__ A_log,  // [INNER, L]
    float* __restrict__ Aprod,        // [NCHUNK, INNER, L]
    float* __restrict__ Hend) {       // [NCHUNK, INNER, L]
  const int tid = threadIdx.x;
  const int l = tid & 15;
  const int d = blockIdx.y * 16 + (tid >> 4);
  const int c = blockIdx.x;
  const float a = -expf(A_log[d * LSTATE + l]);
  float h = 0.f, ap = 1.f;
  const int s0 = c * CHUNK;
  #pragma unroll 4
  for (int i = 0; i < CHUNK; ++i) {
    int s = s0 + i;
    float dv  = delta[(size_t)s * INNER + d];
    float xcv = xc[(size_t)s * INNER + d];
    float bm  = xp[(size_t)s * XPW + DRANK + l];
    float dA  = expf(dv * a);
    h = dA * h + dv * bm * xcv;
    ap *= dA;
  }
  size_t o = ((size_t)c * INNER + d) * LSTATE + l;
  Aprod[o] = ap;
  Hend[o] = h;
}

__global__ __launch_bounds__(256) void scan_pass2(
    const float* __restrict__ Aprod, const float* __restrict__ Hend,
    float* __restrict__ Hin) {        // [NCHUNK, INNER, L] carry-in per chunk
  const int idx = blockIdx.x * 256 + threadIdx.x;   // flat (d,l)
  float h = 0.f;
  for (int c = 0; c < NCHUNK; ++c) {
    size_t o = (size_t)c * INNER * LSTATE + idx;
    Hin[o] = h;
    h = Aprod[o] * h + Hend[o];
  }
}

__global__ __launch_bounds__(256) void scan_pass3(
    const float* __restrict__ delta,
    const float* __restrict__ xp,
    const float* __restrict__ xc,
    const float* __restrict__ xz,     // [S, 2*INNER]; z = cols [INNER, 2*INNER)
    const float* __restrict__ A_log,
    const float* __restrict__ Dvec,
    const float* __restrict__ Hin,
    float* __restrict__ y) {          // [S, INNER]
  const int tid = threadIdx.x;
  const int l = tid & 15;
  const int d = blockIdx.y * 16 + (tid >> 4);
  const int c = blockIdx.x;
  const float a = -expf(A_log[d * LSTATE + l]);
  const float Dd = Dvec[d];
  float h = Hin[((size_t)c * INNER + d) * LSTATE + l];
  const int s0 = c * CHUNK;
  #pragma unroll 2
  for (int i = 0; i < CHUNK; ++i) {
    int s = s0 + i;
    float dv  = delta[(size_t)s * INNER + d];
    float xcv = xc[(size_t)s * INNER + d];
    float bm  = xp[(size_t)s * XPW + DRANK + l];
    float cm  = xp[(size_t)s * XPW + DRANK + LSTATE + l];
    float dA  = expf(dv * a);
    h = dA * h + dv * bm * xcv;
    float contrib = h * cm;
    contrib += __shfl_xor(contrib, 1);
    contrib += __shfl_xor(contrib, 2);
    contrib += __shfl_xor(contrib, 4);
    contrib += __shfl_xor(contrib, 8);
    if (l == 0) {
      float zv = xz[(size_t)s * (2 * INNER) + INNER + d];
      float silu_z = zv / (1.f + expf(-zv));
      y[(size_t)s * INNER + d] = (contrib + xcv * Dd) * silu_z;
    }
  }
}

extern "C" void kernel_launch(void* const* d_in, const int* in_sizes, int n_in,
                              void* d_out, int out_size, void* d_ws, size_t ws_size,
                              hipStream_t stream) {
  const float* x      = (const float*)d_in[0];   // [S, HID]
  const float* W_in   = (const float*)d_in[1];   // [HID, 2*INNER]
  const float* conv_w = (const float*)d_in[2];   // [4,1,INNER]
  const float* conv_b = (const float*)d_in[3];   // [INNER]
  const float* W_x    = (const float*)d_in[4];   // [INNER, 96]
  const float* W_delta= (const float*)d_in[5];   // [DRANK, INNER]
  const float* b_delta= (const float*)d_in[6];   // [INNER]
  const float* A_log  = (const float*)d_in[7];   // [INNER, L]
  const float* Dvec   = (const float*)d_in[8];   // [INNER]
  const float* W_out  = (const float*)d_in[9];   // [INNER, HID]
  float* out = (float*)d_out;

  float* ws    = (float*)d_ws;
  float* xz    = ws;                               // S * 2*INNER
  float* xc    = xz + (size_t)S_LEN * 2 * INNER;   // S * INNER
  float* xp    = xc + (size_t)S_LEN * INNER;       // S * 96
  float* delta = xp + (size_t)S_LEN * XPW;         // S * INNER
  float* y     = delta + (size_t)S_LEN * INNER;    // S * INNER
  float* Aprod = y + (size_t)S_LEN * INNER;        // NCHUNK * INNER * L
  float* Hend  = Aprod + (size_t)NCHUNK * INNER * LSTATE;
  float* Hin   = Hend  + (size_t)NCHUNK * INNER * LSTATE;

  // 1. xz = x @ W_in   (M=2048, N=4096, K=1024)
  gemm_tiled<0><<<dim3(4096 / 64, 2048 / 64), 256, 0, stream>>>(
      x, HID, W_in, 2 * INNER, xz, 2 * INNER, S_LEN, 2 * INNER, HID, nullptr);

  // 2. xc = silu(causal_depthwise_conv(xi) + conv_b)
  conv_silu_kernel<<<(S_LEN * INNER + 255) / 256, 256, 0, stream>>>(
      xz, conv_w, conv_b, xc);

  // 3. xp = xc @ W_x   (M=2048, N=96, K=2048)
  gemm_xp_kernel<<<S_LEN / 16, 256, 0, stream>>>(xc, W_x, xp);

  // 4. delta = softplus(xp[:, :64] @ W_delta + b_delta)  (M=2048, N=2048, K=64)
  gemm_tiled<1><<<dim3(2048 / 64, 2048 / 64), 256, 0, stream>>>(
      xp, XPW, W_delta, INNER, delta, INNER, S_LEN, INNER, DRANK, b_delta);

  // 5. chunk-parallel SSM scan -> y (fused with +xc*D and *silu(z))
  scan_pass1<<<dim3(NCHUNK, INNER / 16), 256, 0, stream>>>(
      delta, xp, xc, A_log, Aprod, Hend);
  scan_pass2<<<(INNER * LSTATE) / 256, 256, 0, stream>>>(Aprod, Hend, Hin);
  scan_pass3<<<dim3(NCHUNK, INNER / 16), 256, 0, stream>>>(
      delta, xp, xc, xz, A_log, Dvec, Hin, y);

  // 6. out = y @ W_out  (M=2048, N=1024, K=2048)
  gemm_tiled<0><<<dim3(1024 / 64, 2048 / 64), 256, 0, stream>>>(
      y, INNER, W_out, HID, out, HID, S_LEN, HID, INNER, nullptr);
}

// Round 3
// 603.068 us; speedup vs baseline: 4.5248x; 2.0265x over previous
//
#include <hip/hip_runtime.h>
#include <hip/hip_bf16.h>
#include <math.h>

#define S_LEN 2048
#define HID   1024
#define INNER 2048
#define NCONV 4
#define LSTATE 16
#define DRANK 64
#define XPW   96   // DRANK + 2*LSTATE
#define CHUNK 32
#define NCHUNK (S_LEN / CHUNK)   // 64

typedef __attribute__((ext_vector_type(8))) short bf16x8;
typedef __attribute__((ext_vector_type(4))) float f32x4;

__device__ __forceinline__ short f2bf(float f) {
  union { __hip_bfloat16 h; short s; } u;
  u.h = __float2bfloat16(f);
  return u.s;
}

// ----------------------- fp32 -> bf16 cast (vectorized) ---------------------
__global__ __launch_bounds__(256) void cast_bf16_kernel(
    const float* __restrict__ in, short* __restrict__ out, int n4) {
  int i = blockIdx.x * 256 + threadIdx.x;
  if (i >= n4) return;
  const float4 v = ((const float4*)in)[i];
  short4 o;
  o.x = f2bf(v.x); o.y = f2bf(v.y); o.z = f2bf(v.z); o.w = f2bf(v.w);
  ((short4*)out)[i] = o;
}

// ---------------- transpose + cast: in[R][C] f32 -> out[C][R] bf16 ----------
__global__ __launch_bounds__(256) void transpose_cast_kernel(
    const float* __restrict__ in, short* __restrict__ out, int R, int C) {
  __shared__ float tile[32][33];
  const int bc = blockIdx.x * 32, br = blockIdx.y * 32;
  const int tx = threadIdx.x & 31, ty = threadIdx.x >> 5;   // 32 x 8
  #pragma unroll
  for (int i = 0; i < 32; i += 8)
    tile[ty + i][tx] = in[(size_t)(br + ty + i) * C + bc + tx];
  __syncthreads();
  #pragma unroll
  for (int i = 0; i < 32; i += 8)
    out[(size_t)(bc + ty + i) * R + br + tx] = f2bf(tile[tx][ty + i]);
}

// --------------- bf16 MFMA GEMM: C[M,N] = A[M,K] @ Bt[N,K]^T ---------------
// 128x128 tile, BK=32, 4 waves (2x2), each wave 64x64 = 4x4 frags of 16x16x32.
#define BK    32
#define PADK  40   // shorts per LDS row (80 B): staging writes conflict-free,
                   // fragment reads 2-way (free per m136)
__global__ __launch_bounds__(256) void gemm_bf16(
    const short* __restrict__ A,  int lda,    // [M,K] bf16 row-major
    const short* __restrict__ Bt, int ldb,    // [N,K] bf16 row-major
    float* __restrict__ C, int ldc, int K) {
  __shared__ short As[128 * PADK];
  __shared__ short Bs[128 * PADK];
  const int tid  = threadIdx.x;
  const int lane = tid & 63;
  const int wave = tid >> 6;
  const int bm = blockIdx.y * 128;
  const int bn = blockIdx.x * 128;
  const int wm = (wave & 1) * 64;
  const int wn = (wave >> 1) * 64;
  const int fr = lane & 15;        // fragment row/col within 16
  const int fq = lane >> 4;        // k-slice quadrant (0..3)

  f32x4 acc[4][4] = {};

  // staging decomposition: 512 16B units per tile; unit u -> row=u>>2, ks=u&3
  const int r0 = tid >> 1;               // unit tid:   rows 0..127 (2 units/row)
  const int s0 = (tid & 1) * 2;          // k-slices {0,1} or {2,3}... use 2 units
  for (int k0 = 0; k0 < K; k0 += BK) {
    // each thread stages 2 units of A and 2 of B
    {
      const bf16x8 va0 = *(const bf16x8*)(A + (size_t)(bm + r0) * lda + k0 + (s0 + 0) * 8);
      const bf16x8 va1 = *(const bf16x8*)(A + (size_t)(bm + r0) * lda + k0 + (s0 + 1) * 8);
      *(bf16x8*)(&As[r0 * PADK + (s0 + 0) * 8]) = va0;
      *(bf16x8*)(&As[r0 * PADK + (s0 + 1) * 8]) = va1;
      const bf16x8 vb0 = *(const bf16x8*)(Bt + (size_t)(bn + r0) * ldb + k0 + (s0 + 0) * 8);
      const bf16x8 vb1 = *(const bf16x8*)(Bt + (size_t)(bn + r0) * ldb + k0 + (s0 + 1) * 8);
      *(bf16x8*)(&Bs[r0 * PADK + (s0 + 0) * 8]) = vb0;
      *(bf16x8*)(&Bs[r0 * PADK + (s0 + 1) * 8]) = vb1;
    }
    __syncthreads();
    bf16x8 af[4], bfv[4];
    #pragma unroll
    for (int mi = 0; mi < 4; ++mi)
      af[mi] = *(const bf16x8*)(&As[(wm + mi * 16 + fr) * PADK + fq * 8]);
    #pragma unroll
    for (int ni = 0; ni < 4; ++ni)
      bfv[ni] = *(const bf16x8*)(&Bs[(wn + ni * 16 + fr) * PADK + fq * 8]);
    #pragma unroll
    for (int mi = 0; mi < 4; ++mi)
      #pragma unroll
      for (int ni = 0; ni < 4; ++ni)
        acc[mi][ni] = __builtin_amdgcn_mfma_f32_16x16x32_bf16(
            af[mi], bfv[ni], acc[mi][ni], 0, 0, 0);
    __syncthreads();
  }
  // C/D layout (m89): col = lane&15, row = (lane>>4)*4 + reg
  #pragma unroll
  for (int mi = 0; mi < 4; ++mi) {
    #pragma unroll
    for (int ni = 0; ni < 4; ++ni) {
      const int col = bn + wn + ni * 16 + fr;
      #pragma unroll
      for (int r = 0; r < 4; ++r) {
        const int row = bm + wm + mi * 16 + fq * 4 + r;
        C[(size_t)row * ldc + col] = acc[mi][ni][r];
      }
    }
  }
}

// ---------------- generic tiled fp32 GEMM (kept for small GEMMs) ------------
// EPI: 0 = plain store, 1 = softplus(acc + bias) store
template<int EPI>
__global__ __launch_bounds__(256) void gemm_tiled(
    const float* __restrict__ A, int lda,
    const float* __restrict__ B, int ldb,
    float* __restrict__ C, int ldc,
    int M, int N, int K, const float* __restrict__ bias) {
  __shared__ float As[16][65];
  __shared__ float Bs[16][65];
  const int bm = blockIdx.y * 64;
  const int bn = blockIdx.x * 64;
  const int tid = threadIdx.x;
  const int tx = tid & 15;
  const int ty = tid >> 4;
  float acc[4][4] = {};
  for (int k0 = 0; k0 < K; k0 += 16) {
    #pragma unroll
    for (int i = tid; i < 64 * 16; i += 256) {
      int m = i >> 4, kk = i & 15;
      As[kk][m] = A[(size_t)(bm + m) * lda + k0 + kk];
    }
    #pragma unroll
    for (int i = tid; i < 16 * 64; i += 256) {
      int kk = i >> 6, n = i & 63;
      Bs[kk][n] = B[(size_t)(k0 + kk) * ldb + bn + n];
    }
    __syncthreads();
    #pragma unroll
    for (int kk = 0; kk < 16; ++kk) {
      float a[4], b[4];
      #pragma unroll
      for (int i = 0; i < 4; ++i) a[i] = As[kk][ty * 4 + i];
      #pragma unroll
      for (int j = 0; j < 4; ++j) b[j] = Bs[kk][tx * 4 + j];
      #pragma unroll
      for (int i = 0; i < 4; ++i)
        #pragma unroll
        for (int j = 0; j < 4; ++j)
          acc[i][j] += a[i] * b[j];
    }
    __syncthreads();
  }
  #pragma unroll
  for (int i = 0; i < 4; ++i) {
    #pragma unroll
    for (int j = 0; j < 4; ++j) {
      int row = bm + ty * 4 + i;
      int col = bn + tx * 4 + j;
      float v = acc[i][j];
      if (EPI == 1) {
        v += bias[col];
        v = fmaxf(v, 0.f) + log1pf(expf(-fabsf(v)));   // softplus
      }
      C[(size_t)row * ldc + col] = v;
    }
  }
}

// ------------- depthwise causal conv (width 4) + bias + SiLU ----------------
__global__ __launch_bounds__(256) void conv_silu_kernel(
    const float* __restrict__ xz,
    const float* __restrict__ cw,
    const float* __restrict__ cb,
    float* __restrict__ xc) {
  int idx = blockIdx.x * 256 + threadIdx.x;
  if (idx >= S_LEN * INNER) return;
  int s = idx / INNER;
  int c = idx - s * INNER;
  float acc = cb[c];
  #pragma unroll
  for (int k = 0; k < NCONV; ++k) {
    int t = s - (NCONV - 1) + k;
    if (t >= 0) acc += xz[(size_t)t * (2 * INNER) + c] * cw[k * INNER + c];
  }
  xc[idx] = acc / (1.f + expf(-acc));
}

// ------------------ xp = xc[S,INNER] @ W_x[INNER,96] ------------------------
__global__ __launch_bounds__(256) void gemm_xp_kernel(
    const float* __restrict__ xc, const float* __restrict__ Wx,
    float* __restrict__ xp) {
  __shared__ float As[16][33];
  __shared__ float Bs[32][97];
  const int bm = blockIdx.x * 16;
  const int tid = threadIdx.x;
  const int tx = tid & 15;
  const int ty = tid >> 4;
  float acc[6] = {};
  for (int k0 = 0; k0 < INNER; k0 += 32) {
    #pragma unroll
    for (int i = tid; i < 16 * 32; i += 256) {
      int m = i >> 5, kk = i & 31;
      As[m][kk] = xc[(size_t)(bm + m) * INNER + k0 + kk];
    }
    #pragma unroll
    for (int i = tid; i < 32 * 96; i += 256) {
      int kk = i / 96, n = i - kk * 96;
      Bs[kk][n] = Wx[(size_t)(k0 + kk) * XPW + n];
    }
    __syncthreads();
    #pragma unroll
    for (int kk = 0; kk < 32; ++kk) {
      float a = As[ty][kk];
      #pragma unroll
      for (int j = 0; j < 6; ++j) acc[j] += a * Bs[kk][tx * 6 + j];
    }
    __syncthreads();
  }
  #pragma unroll
  for (int j = 0; j < 6; ++j)
    xp[(size_t)(bm + ty) * XPW + tx * 6 + j] = acc[j];
}

// ---------------- chunk-parallel SSM scan (3 passes) ------------------------
__global__ __launch_bounds__(256) void scan_pass1(
    const float* __restrict__ delta,
    const float* __restrict__ xp,
    const float* __restrict__ xc,
    const float* __restrict__ A_log,
    float* __restrict__ Aprod,
    float* __restrict__ Hend) {
  const int tid = threadIdx.x;
  const int l = tid & 15;
  const int d = blockIdx.y * 16 + (tid >> 4);
  const int c = blockIdx.x;
  const float a = -expf(A_log[d * LSTATE + l]);
  float h = 0.f, ap = 1.f;
  const int s0 = c * CHUNK;
  #pragma unroll 4
  for (int i = 0; i < CHUNK; ++i) {
    int s = s0 + i;
    float dv  = delta[(size_t)s * INNER + d];
    float xcv = xc[(size_t)s * INNER + d];
    float bm  = xp[(size_t)s * XPW + DRANK + l];
    float dA  = expf(dv * a);
    h = dA * h + dv * bm * xcv;
    ap *= dA;
  }
  size_t o = ((size_t)c * INNER + d) * LSTATE + l;
  Aprod[o] = ap;
  Hend[o] = h;
}

__global__ __launch_bounds__(256) void scan_pass2(
    const float* __restrict__ Aprod, const float* __restrict__ Hend,
    float* __restrict__ Hin) {
  const int idx = blockIdx.x * 256 + threadIdx.x;
  float h = 0.f;
  for (int c = 0; c < NCHUNK; ++c) {
    size_t o = (size_t)c * INNER * LSTATE + idx;
    float ap = Aprod[o], he = Hend[o];
    Hin[o] = h;
    h = ap * h + he;
  }
}

__global__ __launch_bounds__(256) void scan_pass3(
    const float* __restrict__ delta,
    const float* __restrict__ xp,
    const float* __restrict__ xc,
    const float* __restrict__ xz,
    const float* __restrict__ A_log,
    const float* __restrict__ Dvec,
    const float* __restrict__ Hin,
    short* __restrict__ ybf) {        // [S, INNER] bf16 (feeds gemm_bf16)
  const int tid = threadIdx.x;
  const int l = tid & 15;
  const int d = blockIdx.y * 16 + (tid >> 4);
  const int c = blockIdx.x;
  const float a = -expf(A_log[d * LSTATE + l]);
  const float Dd = Dvec[d];
  float h = Hin[((size_t)c * INNER + d) * LSTATE + l];
  const int s0 = c * CHUNK;
  #pragma unroll 2
  for (int i = 0; i < CHUNK; ++i) {
    int s = s0 + i;
    float dv  = delta[(size_t)s * INNER + d];
    float xcv = xc[(size_t)s * INNER + d];
    float bm  = xp[(size_t)s * XPW + DRANK + l];
    float cm  = xp[(size_t)s * XPW + DRANK + LSTATE + l];
    float dA  = expf(dv * a);
    h = dA * h + dv * bm * xcv;
    float contrib = h * cm;
    contrib += __shfl_xor(contrib, 1);
    contrib += __shfl_xor(contrib, 2);
    contrib += __shfl_xor(contrib, 4);
    contrib += __shfl_xor(contrib, 8);
    if (l == 0) {
      float zv = xz[(size_t)s * (2 * INNER) + INNER + d];
      float silu_z = zv / (1.f + expf(-zv));
      ybf[(size_t)s * INNER + d] = f2bf((contrib + xcv * Dd) * silu_z);
    }
  }
}

extern "C" void kernel_launch(void* const* d_in, const int* in_sizes, int n_in,
                              void* d_out, int out_size, void* d_ws, size_t ws_size,
                              hipStream_t stream) {
  const float* x      = (const float*)d_in[0];   // [S, HID]
  const float* W_in   = (const float*)d_in[1];   // [HID, 2*INNER]
  const float* conv_w = (const float*)d_in[2];   // [4,1,INNER]
  const float* conv_b = (const float*)d_in[3];   // [INNER]
  const float* W_x    = (const float*)d_in[4];   // [INNER, 96]
  const float* W_delta= (const float*)d_in[5];   // [DRANK, INNER]
  const float* b_delta= (const float*)d_in[6];   // [INNER]
  const float* A_log  = (const float*)d_in[7];   // [INNER, L]
  const float* Dvec   = (const float*)d_in[8];   // [INNER]
  const float* W_out  = (const float*)d_in[9];   // [INNER, HID]
  float* out = (float*)d_out;

  float* ws    = (float*)d_ws;
  float* xz    = ws;                               // S * 2*INNER
  float* xc    = xz + (size_t)S_LEN * 2 * INNER;   // S * INNER
  float* xp    = xc + (size_t)S_LEN * INNER;       // S * 96
  float* delta = xp + (size_t)S_LEN * XPW;         // S * INNER
  float* Aprod = delta + (size_t)S_LEN * INNER;    // NCHUNK * INNER * L
  float* Hend  = Aprod + (size_t)NCHUNK * INNER * LSTATE;
  float* Hin   = Hend  + (size_t)NCHUNK * INNER * LSTATE;
  short* xb    = (short*)(Hin + (size_t)NCHUNK * INNER * LSTATE); // S*HID bf16
  short* WinT  = xb + (size_t)S_LEN * HID;          // [2*INNER, HID] bf16
  short* WoutT = WinT + (size_t)(2 * INNER) * HID;  // [HID, INNER] bf16
  short* ybf   = WoutT + (size_t)HID * INNER;       // [S, INNER] bf16

  // 0. pre-passes: cast x, transpose+cast weights (deterministic every call)
  cast_bf16_kernel<<<(S_LEN * HID / 4 + 255) / 256, 256, 0, stream>>>(
      x, xb, S_LEN * HID / 4);
  transpose_cast_kernel<<<dim3(2 * INNER / 32, HID / 32), 256, 0, stream>>>(
      W_in, WinT, HID, 2 * INNER);
  transpose_cast_kernel<<<dim3(HID / 32, INNER / 32), 256, 0, stream>>>(
      W_out, WoutT, INNER, HID);

  // 1. xz = x @ W_in   (M=2048, N=4096, K=1024)  [bf16 MFMA]
  gemm_bf16<<<dim3(4096 / 128, 2048 / 128), 256, 0, stream>>>(
      xb, HID, WinT, HID, xz, 2 * INNER, HID);

  // 2. xc = silu(causal_depthwise_conv(xi) + conv_b)
  conv_silu_kernel<<<(S_LEN * INNER + 255) / 256, 256, 0, stream>>>(
      xz, conv_w, conv_b, xc);

  // 3. xp = xc @ W_x   (M=2048, N=96, K=2048)
  gemm_xp_kernel<<<S_LEN / 16, 256, 0, stream>>>(xc, W_x, xp);

  // 4. delta = softplus(xp[:, :64] @ W_delta + b_delta)
  gemm_tiled<1><<<dim3(2048 / 64, 2048 / 64), 256, 0, stream>>>(
      xp, XPW, W_delta, INNER, delta, INNER, S_LEN, INNER, DRANK, b_delta);

  // 5. chunk-parallel SSM scan -> ybf (fused +xc*D, *silu(z), bf16 cast)
  scan_pass1<<<dim3(NCHUNK, INNER / 16), 256, 0, stream>>>(
      delta, xp, xc, A_log, Aprod, Hend);
  scan_pass2<<<(INNER * LSTATE) / 256, 256, 0, stream>>>(Aprod, Hend, Hin);
  scan_pass3<<<dim3(NCHUNK, INNER / 16), 256, 0, stream>>>(
      delta, xp, xc, xz, A_log, Dvec, Hin, ybf);

  // 6. out = y @ W_out  (M=2048, N=1024, K=2048)  [bf16 MFMA]
  gemm_bf16<<<dim3(1024 / 128, 2048 / 128), 256, 0, stream>>>(
      ybf, INNER, WoutT, INNER, out, HID, INNER);
}

// Round 4
// 326.853 us; speedup vs baseline: 8.3486x; 1.8451x over previous
//
#include <hip/hip_runtime.h>
#include <hip/hip_bf16.h>
#include <math.h>

#define S_LEN 2048
#define HID   1024
#define INNER 2048
#define NCONV 4
#define LSTATE 16
#define DRANK 64
#define XPW   96   // DRANK + 2*LSTATE
#define CHUNK 32
#define NCHUNK (S_LEN / CHUNK)   // 64
#define XPAD  128  // padded N for the xp GEMM tile

typedef __attribute__((ext_vector_type(8))) short bf16x8;
typedef __attribute__((ext_vector_type(4))) float f32x4;

__device__ __forceinline__ short f2bf(float f) {
  union { __hip_bfloat16 h; short s; } u;
  u.h = __float2bfloat16(f);
  return u.s;
}

// ----------------------- fp32 -> bf16 cast (vectorized) ---------------------
__global__ __launch_bounds__(256) void cast_bf16_kernel(
    const float* __restrict__ in, short* __restrict__ out, int n4) {
  int i = blockIdx.x * 256 + threadIdx.x;
  if (i >= n4) return;
  const float4 v = ((const float4*)in)[i];
  short4 o;
  o.x = f2bf(v.x); o.y = f2bf(v.y); o.z = f2bf(v.z); o.w = f2bf(v.w);
  ((short4*)out)[i] = o;
}

// ------- transpose + cast: in[R][C] f32 -> out[Cpad][R] bf16 (pad rows = 0) -
// grid: (Cpad/32, R/32); reads guarded col<C.
__global__ __launch_bounds__(256) void transpose_cast_kernel(
    const float* __restrict__ in, short* __restrict__ out, int R, int C) {
  __shared__ float tile[32][33];
  const int bc = blockIdx.x * 32, br = blockIdx.y * 32;
  const int tx = threadIdx.x & 31, ty = threadIdx.x >> 5;   // 32 x 8
  #pragma unroll
  for (int i = 0; i < 32; i += 8)
    tile[ty + i][tx] = (bc + tx < C)
        ? in[(size_t)(br + ty + i) * C + bc + tx] : 0.f;
  __syncthreads();
  #pragma unroll
  for (int i = 0; i < 32; i += 8)
    out[(size_t)(bc + ty + i) * R + br + tx] = f2bf(tile[tx][ty + i]);
}

// --------------- bf16 MFMA GEMM: C[M,N] = A[M,K] @ Bt[N,K]^T ---------------
// 128x128 tile, BK=32, 4 waves (2x2), each wave 64x64 = 4x4 frags of 16x16x32.
// Optional K-split over blockIdx.z: each z handles kPerSplit of K and writes
// its own C slice at C + z*cSliceStride (deterministic two-stage reduction).
#define BK    32
#define PADK  40   // shorts per LDS row (80 B): staging writes conflict-free,
                   // fragment reads 2-way (free per m136)
__global__ __launch_bounds__(256) void gemm_bf16(
    const short* __restrict__ A,  int lda,    // [M,K] bf16 row-major
    const short* __restrict__ Bt, int ldb,    // [N,K] bf16 row-major
    float* __restrict__ C, int ldc,
    int kPerSplit, size_t cSliceStride) {
  __shared__ short As[128 * PADK];
  __shared__ short Bs[128 * PADK];
  const int tid  = threadIdx.x;
  const int lane = tid & 63;
  const int wave = tid >> 6;
  const int bm = blockIdx.y * 128;
  const int bn = blockIdx.x * 128;
  const int wm = (wave & 1) * 64;
  const int wn = (wave >> 1) * 64;
  const int fr = lane & 15;        // fragment row/col within 16
  const int fq = lane >> 4;        // k-slice quadrant (0..3)
  const int kbeg = blockIdx.z * kPerSplit;
  const int kend = kbeg + kPerSplit;
  float* Cw = C + (size_t)blockIdx.z * cSliceStride;

  f32x4 acc[4][4] = {};

  const int r0 = tid >> 1;               // rows 0..127 (2 threads/row)
  const int s0 = (tid & 1) * 2;          // k-slice pairs {0,1} / {2,3}
  for (int k0 = kbeg; k0 < kend; k0 += BK) {
    {
      const bf16x8 va0 = *(const bf16x8*)(A + (size_t)(bm + r0) * lda + k0 + (s0 + 0) * 8);
      const bf16x8 va1 = *(const bf16x8*)(A + (size_t)(bm + r0) * lda + k0 + (s0 + 1) * 8);
      *(bf16x8*)(&As[r0 * PADK + (s0 + 0) * 8]) = va0;
      *(bf16x8*)(&As[r0 * PADK + (s0 + 1) * 8]) = va1;
      const bf16x8 vb0 = *(const bf16x8*)(Bt + (size_t)(bn + r0) * ldb + k0 + (s0 + 0) * 8);
      const bf16x8 vb1 = *(const bf16x8*)(Bt + (size_t)(bn + r0) * ldb + k0 + (s0 + 1) * 8);
      *(bf16x8*)(&Bs[r0 * PADK + (s0 + 0) * 8]) = vb0;
      *(bf16x8*)(&Bs[r0 * PADK + (s0 + 1) * 8]) = vb1;
    }
    __syncthreads();
    bf16x8 af[4], bfv[4];
    #pragma unroll
    for (int mi = 0; mi < 4; ++mi)
      af[mi] = *(const bf16x8*)(&As[(wm + mi * 16 + fr) * PADK + fq * 8]);
    #pragma unroll
    for (int ni = 0; ni < 4; ++ni)
      bfv[ni] = *(const bf16x8*)(&Bs[(wn + ni * 16 + fr) * PADK + fq * 8]);
    #pragma unroll
    for (int mi = 0; mi < 4; ++mi)
      #pragma unroll
      for (int ni = 0; ni < 4; ++ni)
        acc[mi][ni] = __builtin_amdgcn_mfma_f32_16x16x32_bf16(
            af[mi], bfv[ni], acc[mi][ni], 0, 0, 0);
    __syncthreads();
  }
  // C/D layout (m89): col = lane&15, row = (lane>>4)*4 + reg
  #pragma unroll
  for (int mi = 0; mi < 4; ++mi) {
    #pragma unroll
    for (int ni = 0; ni < 4; ++ni) {
      const int col = bn + wn + ni * 16 + fr;
      #pragma unroll
      for (int r = 0; r < 4; ++r) {
        const int row = bm + wm + mi * 16 + fq * 4 + r;
        Cw[(size_t)row * ldc + col] = acc[mi][ni][r];
      }
    }
  }
}

// ------- reduce 4 K-split partials [4][S][XPAD] -> xp [S][XPW] --------------
__global__ __launch_bounds__(256) void reduce_xp_kernel(
    const float* __restrict__ part, float* __restrict__ xp) {
  // float4 granularity: S*24 vectors of 4
  int i4 = blockIdx.x * 256 + threadIdx.x;
  if (i4 >= S_LEN * (XPW / 4)) return;
  int m = i4 / (XPW / 4);
  int n4 = i4 - m * (XPW / 4);
  const float4* p = (const float4*)part;
  const size_t rowv = (size_t)m * (XPAD / 4) + n4;
  const size_t slice = (size_t)S_LEN * (XPAD / 4);
  float4 a = p[rowv], b = p[rowv + slice], c = p[rowv + 2 * slice], d = p[rowv + 3 * slice];
  float4 o;
  o.x = (a.x + b.x) + (c.x + d.x);
  o.y = (a.y + b.y) + (c.y + d.y);
  o.z = (a.z + b.z) + (c.z + d.z);
  o.w = (a.w + b.w) + (c.w + d.w);
  ((float4*)xp)[i4] = o;
}

// ---------------- generic tiled fp32 GEMM (kept for delta GEMM) -------------
template<int EPI>
__global__ __launch_bounds__(256) void gemm_tiled(
    const float* __restrict__ A, int lda,
    const float* __restrict__ B, int ldb,
    float* __restrict__ C, int ldc,
    int M, int N, int K, const float* __restrict__ bias) {
  __shared__ float As[16][65];
  __shared__ float Bs[16][65];
  const int bm = blockIdx.y * 64;
  const int bn = blockIdx.x * 64;
  const int tid = threadIdx.x;
  const int tx = tid & 15;
  const int ty = tid >> 4;
  float acc[4][4] = {};
  for (int k0 = 0; k0 < K; k0 += 16) {
    #pragma unroll
    for (int i = tid; i < 64 * 16; i += 256) {
      int m = i >> 4, kk = i & 15;
      As[kk][m] = A[(size_t)(bm + m) * lda + k0 + kk];
    }
    #pragma unroll
    for (int i = tid; i < 16 * 64; i += 256) {
      int kk = i >> 6, n = i & 63;
      Bs[kk][n] = B[(size_t)(k0 + kk) * ldb + bn + n];
    }
    __syncthreads();
    #pragma unroll
    for (int kk = 0; kk < 16; ++kk) {
      float a[4], b[4];
      #pragma unroll
      for (int i = 0; i < 4; ++i) a[i] = As[kk][ty * 4 + i];
      #pragma unroll
      for (int j = 0; j < 4; ++j) b[j] = Bs[kk][tx * 4 + j];
      #pragma unroll
      for (int i = 0; i < 4; ++i)
        #pragma unroll
        for (int j = 0; j < 4; ++j)
          acc[i][j] += a[i] * b[j];
    }
    __syncthreads();
  }
  #pragma unroll
  for (int i = 0; i < 4; ++i) {
    #pragma unroll
    for (int j = 0; j < 4; ++j) {
      int row = bm + ty * 4 + i;
      int col = bn + tx * 4 + j;
      float v = acc[i][j];
      if (EPI == 1) {
        v += bias[col];
        v = fmaxf(v, 0.f) + log1pf(expf(-fabsf(v)));   // softplus
      }
      C[(size_t)row * ldc + col] = v;
    }
  }
}

// ------------- depthwise causal conv (width 4) + bias + SiLU ----------------
// writes fp32 xc (for scan) and bf16 xcb (for the xp MFMA GEMM)
__global__ __launch_bounds__(256) void conv_silu_kernel(
    const float* __restrict__ xz,
    const float* __restrict__ cw,
    const float* __restrict__ cb,
    float* __restrict__ xc,
    short* __restrict__ xcb) {
  int idx = blockIdx.x * 256 + threadIdx.x;
  if (idx >= S_LEN * INNER) return;
  int s = idx / INNER;
  int c = idx - s * INNER;
  float acc = cb[c];
  #pragma unroll
  for (int k = 0; k < NCONV; ++k) {
    int t = s - (NCONV - 1) + k;
    if (t >= 0) acc += xz[(size_t)t * (2 * INNER) + c] * cw[k * INNER + c];
  }
  float v = acc / (1.f + expf(-acc));
  xc[idx] = v;
  xcb[idx] = f2bf(v);
}

// ---------------- chunk-parallel SSM scan (3 passes) ------------------------
__global__ __launch_bounds__(256) void scan_pass1(
    const float* __restrict__ delta,
    const float* __restrict__ xp,
    const float* __restrict__ xc,
    const float* __restrict__ A_log,
    float* __restrict__ Aprod,
    float* __restrict__ Hend) {
  const int tid = threadIdx.x;
  const int l = tid & 15;
  const int d = blockIdx.y * 16 + (tid >> 4);
  const int c = blockIdx.x;
  const float a = -expf(A_log[d * LSTATE + l]);
  float h = 0.f, ap = 1.f;
  const int s0 = c * CHUNK;
  #pragma unroll 4
  for (int i = 0; i < CHUNK; ++i) {
    int s = s0 + i;
    float dv  = delta[(size_t)s * INNER + d];
    float xcv = xc[(size_t)s * INNER + d];
    float bm  = xp[(size_t)s * XPW + DRANK + l];
    float dA  = expf(dv * a);
    h = dA * h + dv * bm * xcv;
    ap *= dA;
  }
  size_t o = ((size_t)c * INNER + d) * LSTATE + l;
  Aprod[o] = ap;
  Hend[o] = h;
}

__global__ __launch_bounds__(256) void scan_pass2(
    const float* __restrict__ Aprod, const float* __restrict__ Hend,
    float* __restrict__ Hin) {
  const int idx = blockIdx.x * 256 + threadIdx.x;
  float h = 0.f;
  for (int c = 0; c < NCHUNK; ++c) {
    size_t o = (size_t)c * INNER * LSTATE + idx;
    float ap = Aprod[o], he = Hend[o];
    Hin[o] = h;
    h = ap * h + he;
  }
}

__global__ __launch_bounds__(256) void scan_pass3(
    const float* __restrict__ delta,
    const float* __restrict__ xp,
    const float* __restrict__ xc,
    const float* __restrict__ xz,
    const float* __restrict__ A_log,
    const float* __restrict__ Dvec,
    const float* __restrict__ Hin,
    short* __restrict__ ybf) {        // [S, INNER] bf16 (feeds gemm_bf16)
  const int tid = threadIdx.x;
  const int l = tid & 15;
  const int d = blockIdx.y * 16 + (tid >> 4);
  const int c = blockIdx.x;
  const float a = -expf(A_log[d * LSTATE + l]);
  const float Dd = Dvec[d];
  float h = Hin[((size_t)c * INNER + d) * LSTATE + l];
  const int s0 = c * CHUNK;
  #pragma unroll 2
  for (int i = 0; i < CHUNK; ++i) {
    int s = s0 + i;
    float dv  = delta[(size_t)s * INNER + d];
    float xcv = xc[(size_t)s * INNER + d];
    float bm  = xp[(size_t)s * XPW + DRANK + l];
    float cm  = xp[(size_t)s * XPW + DRANK + LSTATE + l];
    float dA  = expf(dv * a);
    h = dA * h + dv * bm * xcv;
    float contrib = h * cm;
    contrib += __shfl_xor(contrib, 1);
    contrib += __shfl_xor(contrib, 2);
    contrib += __shfl_xor(contrib, 4);
    contrib += __shfl_xor(contrib, 8);
    if (l == 0) {
      float zv = xz[(size_t)s * (2 * INNER) + INNER + d];
      float silu_z = zv / (1.f + expf(-zv));
      ybf[(size_t)s * INNER + d] = f2bf((contrib + xcv * Dd) * silu_z);
    }
  }
}

extern "C" void kernel_launch(void* const* d_in, const int* in_sizes, int n_in,
                              void* d_out, int out_size, void* d_ws, size_t ws_size,
                              hipStream_t stream) {
  const float* x      = (const float*)d_in[0];   // [S, HID]
  const float* W_in   = (const float*)d_in[1];   // [HID, 2*INNER]
  const float* conv_w = (const float*)d_in[2];   // [4,1,INNER]
  const float* conv_b = (const float*)d_in[3];   // [INNER]
  const float* W_x    = (const float*)d_in[4];   // [INNER, 96]
  const float* W_delta= (const float*)d_in[5];   // [DRANK, INNER]
  const float* b_delta= (const float*)d_in[6];   // [INNER]
  const float* A_log  = (const float*)d_in[7];   // [INNER, L]
  const float* Dvec   = (const float*)d_in[8];   // [INNER]
  const float* W_out  = (const float*)d_in[9];   // [INNER, HID]
  float* out = (float*)d_out;

  float* ws    = (float*)d_ws;
  float* xz    = ws;                               // S * 2*INNER
  float* xc    = xz + (size_t)S_LEN * 2 * INNER;   // S * INNER
  float* xp    = xc + (size_t)S_LEN * INNER;       // S * XPW
  float* delta = xp + (size_t)S_LEN * XPW;         // S * INNER
  float* Aprod = delta + (size_t)S_LEN * INNER;    // NCHUNK * INNER * L
  float* Hend  = Aprod + (size_t)NCHUNK * INNER * LSTATE;
  float* Hin   = Hend  + (size_t)NCHUNK * INNER * LSTATE;
  short* xb    = (short*)(Hin + (size_t)NCHUNK * INNER * LSTATE); // S*HID bf16
  short* WinT  = xb + (size_t)S_LEN * HID;          // [2*INNER, HID] bf16
  short* WoutT = WinT + (size_t)(2 * INNER) * HID;  // [HID, INNER] bf16
  short* ybf   = WoutT + (size_t)HID * INNER;       // [S, INNER] bf16
  short* xcb   = ybf + (size_t)S_LEN * INNER;       // [S, INNER] bf16
  short* WxT   = xcb + (size_t)S_LEN * INNER;       // [XPAD, INNER] bf16
  // K-split partials [4][S][XPAD] alias the Aprod region (dead until pass1;
  // Aprod+Hend = 4M floats >> 1M needed)
  float* xpPart = Aprod;

  // 0. pre-passes: cast x, transpose+cast weights (deterministic every call)
  cast_bf16_kernel<<<(S_LEN * HID / 4 + 255) / 256, 256, 0, stream>>>(
      x, xb, S_LEN * HID / 4);
  transpose_cast_kernel<<<dim3(2 * INNER / 32, HID / 32), 256, 0, stream>>>(
      W_in, WinT, HID, 2 * INNER);
  transpose_cast_kernel<<<dim3(HID / 32, INNER / 32), 256, 0, stream>>>(
      W_out, WoutT, INNER, HID);
  transpose_cast_kernel<<<dim3(XPAD / 32, INNER / 32), 256, 0, stream>>>(
      W_x, WxT, INNER, XPW);   // pad rows 96..127 zeroed

  // 1. xz = x @ W_in   (M=2048, N=4096, K=1024)  [bf16 MFMA]
  gemm_bf16<<<dim3(4096 / 128, 2048 / 128, 1), 256, 0, stream>>>(
      xb, HID, WinT, HID, xz, 2 * INNER, HID, 0);

  // 2. xc = silu(causal_depthwise_conv(xi) + conv_b)  (+ bf16 copy)
  conv_silu_kernel<<<(S_LEN * INNER + 255) / 256, 256, 0, stream>>>(
      xz, conv_w, conv_b, xc, xcb);

  // 3. xp = xc @ W_x   (M=2048, N=96, K=2048)  [bf16 MFMA, 4-way K-split]
  gemm_bf16<<<dim3(1, 2048 / 128, 4), 256, 0, stream>>>(
      xcb, INNER, WxT, INNER, xpPart, XPAD, INNER / 4,
      (size_t)S_LEN * XPAD);
  reduce_xp_kernel<<<(S_LEN * (XPW / 4) + 255) / 256, 256, 0, stream>>>(
      xpPart, xp);

  // 4. delta = softplus(xp[:, :64] @ W_delta + b_delta)
  gemm_tiled<1><<<dim3(2048 / 64, 2048 / 64), 256, 0, stream>>>(
      xp, XPW, W_delta, INNER, delta, INNER, S_LEN, INNER, DRANK, b_delta);

  // 5. chunk-parallel SSM scan -> ybf (fused +xc*D, *silu(z), bf16 cast)
  scan_pass1<<<dim3(NCHUNK, INNER / 16), 256, 0, stream>>>(
      delta, xp, xc, A_log, Aprod, Hend);
  scan_pass2<<<(INNER * LSTATE) / 256, 256, 0, stream>>>(Aprod, Hend, Hin);
  scan_pass3<<<dim3(NCHUNK, INNER / 16), 256, 0, stream>>>(
      delta, xp, xc, xz, A_log, Dvec, Hin, ybf);

  // 6. out = y @ W_out  (M=2048, N=1024, K=2048)  [bf16 MFMA]
  gemm_bf16<<<dim3(1024 / 128, 2048 / 128, 1), 256, 0, stream>>>(
      ybf, INNER, WoutT, INNER, out, HID, INNER, 0);
}

// Round 7
// 306.568 us; speedup vs baseline: 8.9010x; 1.0662x over previous
//
#include <hip/hip_runtime.h>
#include <hip/hip_bf16.h>
#include <math.h>

#define S_LEN 2048
#define HID   1024
#define INNER 2048
#define NCONV 4
#define LSTATE 16
#define DRANK 64
#define XPW   96   // DRANK + 2*LSTATE
#define CHUNK 32
#define NCHUNK (S_LEN / CHUNK)   // 64
#define XPAD  128  // padded N for the xp GEMM tile

typedef __attribute__((ext_vector_type(8))) short bf16x8;
typedef __attribute__((ext_vector_type(4))) float f32x4;

__device__ __forceinline__ short f2bf(float f) {
  union { __hip_bfloat16 h; short s; } u;
  u.h = __float2bfloat16(f);
  return u.s;
}

// fast exp: v_exp_f32-based (~1-2 ulp) — bf16 noise floor dominates anyway
__device__ __forceinline__ float fexp(float x) { return __expf(x); }

// ----------------------- fp32 -> bf16 cast (vectorized) ---------------------
__global__ __launch_bounds__(256) void cast_bf16_kernel(
    const float* __restrict__ in, short* __restrict__ out, int n4) {
  int i = blockIdx.x * 256 + threadIdx.x;
  if (i >= n4) return;
  const float4 v = ((const float4*)in)[i];
  short4 o;
  o.x = f2bf(v.x); o.y = f2bf(v.y); o.z = f2bf(v.z); o.w = f2bf(v.w);
  ((short4*)out)[i] = o;
}

// ------- transpose + cast: in[R][C] f32 -> out[Cpad][R] bf16 (pad rows = 0) -
__global__ __launch_bounds__(256) void transpose_cast_kernel(
    const float* __restrict__ in, short* __restrict__ out, int R, int C) {
  __shared__ float tile[32][33];
  const int bc = blockIdx.x * 32, br = blockIdx.y * 32;
  const int tx = threadIdx.x & 31, ty = threadIdx.x >> 5;   // 32 x 8
  #pragma unroll
  for (int i = 0; i < 32; i += 8)
    tile[ty + i][tx] = (bc + tx < C)
        ? in[(size_t)(br + ty + i) * C + bc + tx] : 0.f;
  __syncthreads();
  #pragma unroll
  for (int i = 0; i < 32; i += 8)
    out[(size_t)(bc + ty + i) * R + br + tx] = f2bf(tile[tx][ty + i]);
}

// --------------- bf16 MFMA GEMM: C[M,N] = A[M,K] @ Bt[N,K]^T ---------------
// 128x128 tile, BK=32, 4 waves (2x2), each wave 64x64 = 4x4 frags of 16x16x32.
#define BK    32
#define PADK  40   // shorts per LDS row (80 B)
__global__ __launch_bounds__(256) void gemm_bf16(
    const short* __restrict__ A,  int lda,    // [M,K] bf16 row-major
    const short* __restrict__ Bt, int ldb,    // [N,K] bf16 row-major
    float* __restrict__ C, int ldc,
    int kPerSplit, size_t cSliceStride) {
  __shared__ short As[128 * PADK];
  __shared__ short Bs[128 * PADK];
  const int tid  = threadIdx.x;
  const int lane = tid & 63;
  const int wave = tid >> 6;
  const int bm = blockIdx.y * 128;
  const int bn = blockIdx.x * 128;
  const int wm = (wave & 1) * 64;
  const int wn = (wave >> 1) * 64;
  const int fr = lane & 15;
  const int fq = lane >> 4;
  const int kbeg = blockIdx.z * kPerSplit;
  const int kend = kbeg + kPerSplit;
  float* Cw = C + (size_t)blockIdx.z * cSliceStride;

  f32x4 acc[4][4] = {};

  const int r0 = tid >> 1;
  const int s0 = (tid & 1) * 2;
  for (int k0 = kbeg; k0 < kend; k0 += BK) {
    {
      const bf16x8 va0 = *(const bf16x8*)(A + (size_t)(bm + r0) * lda + k0 + (s0 + 0) * 8);
      const bf16x8 va1 = *(const bf16x8*)(A + (size_t)(bm + r0) * lda + k0 + (s0 + 1) * 8);
      *(bf16x8*)(&As[r0 * PADK + (s0 + 0) * 8]) = va0;
      *(bf16x8*)(&As[r0 * PADK + (s0 + 1) * 8]) = va1;
      const bf16x8 vb0 = *(const bf16x8*)(Bt + (size_t)(bn + r0) * ldb + k0 + (s0 + 0) * 8);
      const bf16x8 vb1 = *(const bf16x8*)(Bt + (size_t)(bn + r0) * ldb + k0 + (s0 + 1) * 8);
      *(bf16x8*)(&Bs[r0 * PADK + (s0 + 0) * 8]) = vb0;
      *(bf16x8*)(&Bs[r0 * PADK + (s0 + 1) * 8]) = vb1;
    }
    __syncthreads();
    bf16x8 af[4], bfv[4];
    #pragma unroll
    for (int mi = 0; mi < 4; ++mi)
      af[mi] = *(const bf16x8*)(&As[(wm + mi * 16 + fr) * PADK + fq * 8]);
    #pragma unroll
    for (int ni = 0; ni < 4; ++ni)
      bfv[ni] = *(const bf16x8*)(&Bs[(wn + ni * 16 + fr) * PADK + fq * 8]);
    #pragma unroll
    for (int mi = 0; mi < 4; ++mi)
      #pragma unroll
      for (int ni = 0; ni < 4; ++ni)
        acc[mi][ni] = __builtin_amdgcn_mfma_f32_16x16x32_bf16(
            af[mi], bfv[ni], acc[mi][ni], 0, 0, 0);
    __syncthreads();
  }
  // C/D layout (m89): col = lane&15, row = (lane>>4)*4 + reg
  #pragma unroll
  for (int mi = 0; mi < 4; ++mi) {
    #pragma unroll
    for (int ni = 0; ni < 4; ++ni) {
      const int col = bn + wn + ni * 16 + fr;
      #pragma unroll
      for (int r = 0; r < 4; ++r) {
        const int row = bm + wm + mi * 16 + fq * 4 + r;
        Cw[(size_t)row * ldc + col] = acc[mi][ni][r];
      }
    }
  }
}

// ------- reduce 4 K-split partials [4][S][XPAD] -> xp [S][XPW] --------------
__global__ __launch_bounds__(256) void reduce_xp_kernel(
    const float* __restrict__ part, float* __restrict__ xp) {
  int i4 = blockIdx.x * 256 + threadIdx.x;
  if (i4 >= S_LEN * (XPW / 4)) return;
  int m = i4 / (XPW / 4);
  int n4 = i4 - m * (XPW / 4);
  const float4* p = (const float4*)part;
  const size_t rowv = (size_t)m * (XPAD / 4) + n4;
  const size_t slice = (size_t)S_LEN * (XPAD / 4);
  float4 a = p[rowv], b = p[rowv + slice], c = p[rowv + 2 * slice], d = p[rowv + 3 * slice];
  float4 o;
  o.x = (a.x + b.x) + (c.x + d.x);
  o.y = (a.y + b.y) + (c.y + d.y);
  o.z = (a.z + b.z) + (c.z + d.z);
  o.w = (a.w + b.w) + (c.w + d.w);
  ((float4*)xp)[i4] = o;
}

// ---------------- generic tiled fp32 GEMM (kept for delta GEMM) -------------
template<int EPI>
__global__ __launch_bounds__(256) void gemm_tiled(
    const float* __restrict__ A, int lda,
    const float* __restrict__ B, int ldb,
    float* __restrict__ C, int ldc,
    int M, int N, int K, const float* __restrict__ bias) {
  __shared__ float As[16][65];
  __shared__ float Bs[16][65];
  const int bm = blockIdx.y * 64;
  const int bn = blockIdx.x * 64;
  const int tid = threadIdx.x;
  const int tx = tid & 15;
  const int ty = tid >> 4;
  float acc[4][4] = {};
  for (int k0 = 0; k0 < K; k0 += 16) {
    #pragma unroll
    for (int i = tid; i < 64 * 16; i += 256) {
      int m = i >> 4, kk = i & 15;
      As[kk][m] = A[(size_t)(bm + m) * lda + k0 + kk];
    }
    #pragma unroll
    for (int i = tid; i < 16 * 64; i += 256) {
      int kk = i >> 6, n = i & 63;
      Bs[kk][n] = B[(size_t)(k0 + kk) * ldb + bn + n];
    }
    __syncthreads();
    #pragma unroll
    for (int kk = 0; kk < 16; ++kk) {
      float a[4], b[4];
      #pragma unroll
      for (int i = 0; i < 4; ++i) a[i] = As[kk][ty * 4 + i];
      #pragma unroll
      for (int j = 0; j < 4; ++j) b[j] = Bs[kk][tx * 4 + j];
      #pragma unroll
      for (int i = 0; i < 4; ++i)
        #pragma unroll
        for (int j = 0; j < 4; ++j)
          acc[i][j] += a[i] * b[j];
    }
    __syncthreads();
  }
  #pragma unroll
  for (int i = 0; i < 4; ++i) {
    #pragma unroll
    for (int j = 0; j < 4; ++j) {
      int row = bm + ty * 4 + i;
      int col = bn + tx * 4 + j;
      float v = acc[i][j];
      if (EPI == 1) {
        v += bias[col];
        v = fmaxf(v, 0.f) + log1pf(expf(-fabsf(v)));   // softplus (precise)
      }
      C[(size_t)row * ldc + col] = v;
    }
  }
}

// ------------- depthwise causal conv (width 4) + bias + SiLU ----------------
__global__ __launch_bounds__(256) void conv_silu_kernel(
    const float* __restrict__ xz,
    const float* __restrict__ cw,
    const float* __restrict__ cb,
    float* __restrict__ xc,
    short* __restrict__ xcb) {
  int idx = blockIdx.x * 256 + threadIdx.x;
  if (idx >= S_LEN * INNER) return;
  int s = idx / INNER;
  int c = idx - s * INNER;
  float acc = cb[c];
  #pragma unroll
  for (int k = 0; k < NCONV; ++k) {
    int t = s - (NCONV - 1) + k;
    if (t >= 0) acc += xz[(size_t)t * (2 * INNER) + c] * cw[k * INNER + c];
  }
  float v = acc / (1.f + fexp(-acc));
  xc[idx] = v;
  xcb[idx] = f2bf(v);
}

// ---------------- chunk-parallel SSM scan (3 passes) ------------------------
__global__ __launch_bounds__(256) void scan_pass1(
    const float* __restrict__ delta,
    const float* __restrict__ xp,
    const float* __restrict__ xc,
    const float* __restrict__ A_log,
    float* __restrict__ Aprod,
    float* __restrict__ Hend) {
  const int tid = threadIdx.x;
  const int l = tid & 15;
  const int d = blockIdx.y * 16 + (tid >> 4);
  const int c = blockIdx.x;
  const float a = -fexp(A_log[d * LSTATE + l]);
  float h = 0.f, ap = 1.f;
  const int s0 = c * CHUNK;
  const float* pd = delta + (size_t)s0 * INNER + d;
  const float* px = xc    + (size_t)s0 * INNER + d;
  const float* pb = xp    + (size_t)s0 * XPW + DRANK + l;
  #pragma unroll 4
  for (int i = 0; i < CHUNK; ++i) {
    float dv  = *pd;
    float xcv = *px;
    float bm  = *pb;
    float dA  = fexp(dv * a);
    h = fmaf(dA, h, dv * bm * xcv);
    ap *= dA;
    pd += INNER; px += INNER; pb += XPW;
  }
  size_t o = ((size_t)c * INNER + d) * LSTATE + l;
  Aprod[o] = ap;
  Hend[o] = h;
}

__global__ __launch_bounds__(256) void scan_pass2(
    const float* __restrict__ Aprod, const float* __restrict__ Hend,
    float* __restrict__ Hin) {
  const int idx = blockIdx.x * 256 + threadIdx.x;
  float h = 0.f;
  for (int c = 0; c < NCHUNK; ++c) {
    size_t o = (size_t)c * INNER * LSTATE + idx;
    float ap = Aprod[o], he = Hend[o];
    Hin[o] = h;
    h = ap * h + he;
  }
}

__global__ __launch_bounds__(256) void scan_pass3(
    const float* __restrict__ delta,
    const float* __restrict__ xp,
    const float* __restrict__ xc,
    const float* __restrict__ xz,
    const float* __restrict__ A_log,
    const float* __restrict__ Dvec,
    const float* __restrict__ Hin,
    short* __restrict__ ybf) {        // [S, INNER] bf16 (feeds gemm_bf16)
  const int tid = threadIdx.x;
  const int l = tid & 15;
  const int d = blockIdx.y * 16 + (tid >> 4);
  const int c = blockIdx.x;
  const float a = -fexp(A_log[d * LSTATE + l]);
  const float Dd = Dvec[d];
  float h = Hin[((size_t)c * INNER + d) * LSTATE + l];
  const int s0 = c * CHUNK;
  const float* pd = delta + (size_t)s0 * INNER + d;
  const float* px = xc    + (size_t)s0 * INNER + d;
  const float* pb = xp    + (size_t)s0 * XPW + DRANK + l;
  const float* pc = pb + LSTATE;
  const float* pz = xz + (size_t)s0 * (2 * INNER) + INNER + d;
  short* py = ybf + (size_t)s0 * INNER + d;
  #pragma unroll 2
  for (int i = 0; i < CHUNK; ++i) {
    float dv  = *pd;
    float xcv = *px;
    float bm  = *pb;
    float cm  = *pc;
    float dA  = fexp(dv * a);
    h = fmaf(dA, h, dv * bm * xcv);
    float contrib = h * cm;
    contrib += __shfl_xor(contrib, 1);
    contrib += __shfl_xor(contrib, 2);
    contrib += __shfl_xor(contrib, 4);
    contrib += __shfl_xor(contrib, 8);
    if (l == 0) {
      float zv = *pz;
      float silu_z = zv / (1.f + fexp(-zv));
      *py = f2bf((contrib + xcv * Dd) * silu_z);
    }
    pd += INNER; px += INNER; pb += XPW; pc += XPW;
    pz += 2 * INNER; py += INNER;
  }
}

extern "C" void kernel_launch(void* const* d_in, const int* in_sizes, int n_in,
                              void* d_out, int out_size, void* d_ws, size_t ws_size,
                              hipStream_t stream) {
  const float* x      = (const float*)d_in[0];   // [S, HID]
  const float* W_in   = (const float*)d_in[1];   // [HID, 2*INNER]
  const float* conv_w = (const float*)d_in[2];   // [4,1,INNER]
  const float* conv_b = (const float*)d_in[3];   // [INNER]
  const float* W_x    = (const float*)d_in[4];   // [INNER, 96]
  const float* W_delta= (const float*)d_in[5];   // [DRANK, INNER]
  const float* b_delta= (const float*)d_in[6];   // [INNER]
  const float* A_log  = (const float*)d_in[7];   // [INNER, L]
  const float* Dvec   = (const float*)d_in[8];   // [INNER]
  const float* W_out  = (const float*)d_in[9];   // [INNER, HID]
  float* out = (float*)d_out;

  float* ws    = (float*)d_ws;
  float* xz    = ws;                               // S * 2*INNER
  float* xc    = xz + (size_t)S_LEN * 2 * INNER;   // S * INNER
  float* xp    = xc + (size_t)S_LEN * INNER;       // S * XPW
  float* delta = xp + (size_t)S_LEN * XPW;         // S * INNER
  float* Aprod = delta + (size_t)S_LEN * INNER;    // NCHUNK * INNER * L
  float* Hend  = Aprod + (size_t)NCHUNK * INNER * LSTATE;
  float* Hin   = Hend  + (size_t)NCHUNK * INNER * LSTATE;
  short* xb    = (short*)(Hin + (size_t)NCHUNK * INNER * LSTATE); // S*HID bf16
  short* WinT  = xb + (size_t)S_LEN * HID;          // [2*INNER, HID] bf16
  short* WoutT = WinT + (size_t)(2 * INNER) * HID;  // [HID, INNER] bf16
  short* ybf   = WoutT + (size_t)HID * INNER;       // [S, INNER] bf16
  short* xcb   = ybf + (size_t)S_LEN * INNER;       // [S, INNER] bf16
  short* WxT   = xcb + (size_t)S_LEN * INNER;       // [XPAD, INNER] bf16
  float* xpPart = Aprod;   // K-split partials alias Aprod (dead until pass1)

  // 0. pre-passes
  cast_bf16_kernel<<<(S_LEN * HID / 4 + 255) / 256, 256, 0, stream>>>(
      x, xb, S_LEN * HID / 4);
  transpose_cast_kernel<<<dim3(2 * INNER / 32, HID / 32), 256, 0, stream>>>(
      W_in, WinT, HID, 2 * INNER);
  transpose_cast_kernel<<<dim3(HID / 32, INNER / 32), 256, 0, stream>>>(
      W_out, WoutT, INNER, HID);
  transpose_cast_kernel<<<dim3(XPAD / 32, INNER / 32), 256, 0, stream>>>(
      W_x, WxT, INNER, XPW);   // pad rows 96..127 zeroed

  // 1. xz = x @ W_in   (M=2048, N=4096, K=1024)  [bf16 MFMA]
  gemm_bf16<<<dim3(4096 / 128, 2048 / 128, 1), 256, 0, stream>>>(
      xb, HID, WinT, HID, xz, 2 * INNER, HID, 0);

  // 2. xc = silu(causal_depthwise_conv(xi) + conv_b)  (+ bf16 copy)
  conv_silu_kernel<<<(S_LEN * INNER + 255) / 256, 256, 0, stream>>>(
      xz, conv_w, conv_b, xc, xcb);

  // 3. xp = xc @ W_x   (M=2048, N=96, K=2048)  [bf16 MFMA, 4-way K-split]
  gemm_bf16<<<dim3(1, 2048 / 128, 4), 256, 0, stream>>>(
      xcb, INNER, WxT, INNER, xpPart, XPAD, INNER / 4,
      (size_t)S_LEN * XPAD);
  reduce_xp_kernel<<<(S_LEN * (XPW / 4) + 255) / 256, 256, 0, stream>>>(
      xpPart, xp);

  // 4. delta = softplus(xp[:, :64] @ W_delta + b_delta)
  gemm_tiled<1><<<dim3(2048 / 64, 2048 / 64), 256, 0, stream>>>(
      xp, XPW, W_delta, INNER, delta, INNER, S_LEN, INNER, DRANK, b_delta);

  // 5. chunk-parallel SSM scan -> ybf (fused +xc*D, *silu(z), bf16 cast)
  scan_pass1<<<dim3(NCHUNK, INNER / 16), 256, 0, stream>>>(
      delta, xp, xc, A_log, Aprod, Hend);
  scan_pass2<<<(INNER * LSTATE) / 256, 256, 0, stream>>>(Aprod, Hend, Hin);
  scan_pass3<<<dim3(NCHUNK, INNER / 16), 256, 0, stream>>>(
      delta, xp, xc, xz, A_log, Dvec, Hin, ybf);

  // 6. out = y @ W_out  (M=2048, N=1024, K=2048)  [bf16 MFMA]
  gemm_bf16<<<dim3(1024 / 128, 2048 / 128, 1), 256, 0, stream>>>(
      ybf, INNER, WoutT, INNER, out, HID, INNER, 0);
}

// Round 8
// 224.912 us; speedup vs baseline: 12.1326x; 1.3631x over previous
//
#include <hip/hip_runtime.h>
#include <hip/hip_bf16.h>
#include <math.h>

#define S_LEN 2048
#define HID   1024
#define INNER 2048
#define NCONV 4
#define LSTATE 16
#define DRANK 64
#define XPW   96   // DRANK + 2*LSTATE
#define CHUNK 32
#define NCHUNK (S_LEN / CHUNK)   // 64
#define XPAD  128  // padded N for the xp GEMM tile

typedef __attribute__((ext_vector_type(8))) short bf16x8;
typedef __attribute__((ext_vector_type(4))) float f32x4;

__device__ __forceinline__ short f2bf(float f) {
  union { __hip_bfloat16 h; short s; } u;
  u.h = __float2bfloat16(f);
  return u.s;
}

// fast exp: v_exp_f32-based (~1-2 ulp) — bf16 noise floor dominates anyway
__device__ __forceinline__ float fexp(float x) { return __expf(x); }

// ----------------------- fp32 -> bf16 cast (vectorized) ---------------------
__global__ __launch_bounds__(256) void cast_bf16_kernel(
    const float* __restrict__ in, short* __restrict__ out, int n4) {
  int i = blockIdx.x * 256 + threadIdx.x;
  if (i >= n4) return;
  const float4 v = ((const float4*)in)[i];
  short4 o;
  o.x = f2bf(v.x); o.y = f2bf(v.y); o.z = f2bf(v.z); o.w = f2bf(v.w);
  ((short4*)out)[i] = o;
}

// ------- transpose + cast: in[R][C] f32 -> out[Cpad][R] bf16 (pad rows = 0) -
__global__ __launch_bounds__(256) void transpose_cast_kernel(
    const float* __restrict__ in, short* __restrict__ out, int R, int C) {
  __shared__ float tile[32][33];
  const int bc = blockIdx.x * 32, br = blockIdx.y * 32;
  const int tx = threadIdx.x & 31, ty = threadIdx.x >> 5;   // 32 x 8
  #pragma unroll
  for (int i = 0; i < 32; i += 8)
    tile[ty + i][tx] = (bc + tx < C)
        ? in[(size_t)(br + ty + i) * C + bc + tx] : 0.f;
  __syncthreads();
  #pragma unroll
  for (int i = 0; i < 32; i += 8)
    out[(size_t)(bc + ty + i) * R + br + tx] = f2bf(tile[tx][ty + i]);
}

// --------------- bf16 MFMA GEMM: C[M,N] = A[M,K] @ Bt[N,K]^T ---------------
// 128x128 tile, BK=32, 4 waves (2x2), each wave 64x64 = 4x4 frags of 16x16x32.
#define BK    32
#define PADK  40   // shorts per LDS row (80 B)
__global__ __launch_bounds__(256) void gemm_bf16(
    const short* __restrict__ A,  int lda,    // [M,K] bf16 row-major
    const short* __restrict__ Bt, int ldb,    // [N,K] bf16 row-major
    float* __restrict__ C, int ldc,
    int kPerSplit, size_t cSliceStride) {
  __shared__ short As[128 * PADK];
  __shared__ short Bs[128 * PADK];
  const int tid  = threadIdx.x;
  const int lane = tid & 63;
  const int wave = tid >> 6;
  const int bm = blockIdx.y * 128;
  const int bn = blockIdx.x * 128;
  const int wm = (wave & 1) * 64;
  const int wn = (wave >> 1) * 64;
  const int fr = lane & 15;
  const int fq = lane >> 4;
  const int kbeg = blockIdx.z * kPerSplit;
  const int kend = kbeg + kPerSplit;
  float* Cw = C + (size_t)blockIdx.z * cSliceStride;

  f32x4 acc[4][4] = {};

  const int r0 = tid >> 1;
  const int s0 = (tid & 1) * 2;
  for (int k0 = kbeg; k0 < kend; k0 += BK) {
    {
      const bf16x8 va0 = *(const bf16x8*)(A + (size_t)(bm + r0) * lda + k0 + (s0 + 0) * 8);
      const bf16x8 va1 = *(const bf16x8*)(A + (size_t)(bm + r0) * lda + k0 + (s0 + 1) * 8);
      *(bf16x8*)(&As[r0 * PADK + (s0 + 0) * 8]) = va0;
      *(bf16x8*)(&As[r0 * PADK + (s0 + 1) * 8]) = va1;
      const bf16x8 vb0 = *(const bf16x8*)(Bt + (size_t)(bn + r0) * ldb + k0 + (s0 + 0) * 8);
      const bf16x8 vb1 = *(const bf16x8*)(Bt + (size_t)(bn + r0) * ldb + k0 + (s0 + 1) * 8);
      *(bf16x8*)(&Bs[r0 * PADK + (s0 + 0) * 8]) = vb0;
      *(bf16x8*)(&Bs[r0 * PADK + (s0 + 1) * 8]) = vb1;
    }
    __syncthreads();
    bf16x8 af[4], bfv[4];
    #pragma unroll
    for (int mi = 0; mi < 4; ++mi)
      af[mi] = *(const bf16x8*)(&As[(wm + mi * 16 + fr) * PADK + fq * 8]);
    #pragma unroll
    for (int ni = 0; ni < 4; ++ni)
      bfv[ni] = *(const bf16x8*)(&Bs[(wn + ni * 16 + fr) * PADK + fq * 8]);
    #pragma unroll
    for (int mi = 0; mi < 4; ++mi)
      #pragma unroll
      for (int ni = 0; ni < 4; ++ni)
        acc[mi][ni] = __builtin_amdgcn_mfma_f32_16x16x32_bf16(
            af[mi], bfv[ni], acc[mi][ni], 0, 0, 0);
    __syncthreads();
  }
  // C/D layout (m89): col = lane&15, row = (lane>>4)*4 + reg
  #pragma unroll
  for (int mi = 0; mi < 4; ++mi) {
    #pragma unroll
    for (int ni = 0; ni < 4; ++ni) {
      const int col = bn + wn + ni * 16 + fr;
      #pragma unroll
      for (int r = 0; r < 4; ++r) {
        const int row = bm + wm + mi * 16 + fq * 4 + r;
        Cw[(size_t)row * ldc + col] = acc[mi][ni][r];
      }
    }
  }
}

// ------- reduce 4 K-split partials [4][S][XPAD] -> xp [S][XPW] --------------
__global__ __launch_bounds__(256) void reduce_xp_kernel(
    const float* __restrict__ part, float* __restrict__ xp) {
  int i4 = blockIdx.x * 256 + threadIdx.x;
  if (i4 >= S_LEN * (XPW / 4)) return;
  int m = i4 / (XPW / 4);
  int n4 = i4 - m * (XPW / 4);
  const float4* p = (const float4*)part;
  const size_t rowv = (size_t)m * (XPAD / 4) + n4;
  const size_t slice = (size_t)S_LEN * (XPAD / 4);
  float4 a = p[rowv], b = p[rowv + slice], c = p[rowv + 2 * slice], d = p[rowv + 3 * slice];
  float4 o;
  o.x = (a.x + b.x) + (c.x + d.x);
  o.y = (a.y + b.y) + (c.y + d.y);
  o.z = (a.z + b.z) + (c.z + d.z);
  o.w = (a.w + b.w) + (c.w + d.w);
  ((float4*)xp)[i4] = o;
}

// ---------------- generic tiled fp32 GEMM (kept for delta GEMM) -------------
template<int EPI>
__global__ __launch_bounds__(256) void gemm_tiled(
    const float* __restrict__ A, int lda,
    const float* __restrict__ B, int ldb,
    float* __restrict__ C, int ldc,
    int M, int N, int K, const float* __restrict__ bias) {
  __shared__ float As[16][65];
  __shared__ float Bs[16][65];
  const int bm = blockIdx.y * 64;
  const int bn = blockIdx.x * 64;
  const int tid = threadIdx.x;
  const int tx = tid & 15;
  const int ty = tid >> 4;
  float acc[4][4] = {};
  for (int k0 = 0; k0 < K; k0 += 16) {
    #pragma unroll
    for (int i = tid; i < 64 * 16; i += 256) {
      int m = i >> 4, kk = i & 15;
      As[kk][m] = A[(size_t)(bm + m) * lda + k0 + kk];
    }
    #pragma unroll
    for (int i = tid; i < 16 * 64; i += 256) {
      int kk = i >> 6, n = i & 63;
      Bs[kk][n] = B[(size_t)(k0 + kk) * ldb + bn + n];
    }
    __syncthreads();
    #pragma unroll
    for (int kk = 0; kk < 16; ++kk) {
      float a[4], b[4];
      #pragma unroll
      for (int i = 0; i < 4; ++i) a[i] = As[kk][ty * 4 + i];
      #pragma unroll
      for (int j = 0; j < 4; ++j) b[j] = Bs[kk][tx * 4 + j];
      #pragma unroll
      for (int i = 0; i < 4; ++i)
        #pragma unroll
        for (int j = 0; j < 4; ++j)
          acc[i][j] += a[i] * b[j];
    }
    __syncthreads();
  }
  #pragma unroll
  for (int i = 0; i < 4; ++i) {
    #pragma unroll
    for (int j = 0; j < 4; ++j) {
      int row = bm + ty * 4 + i;
      int col = bn + tx * 4 + j;
      float v = acc[i][j];
      if (EPI == 1) {
        v += bias[col];
        v = fmaxf(v, 0.f) + log1pf(expf(-fabsf(v)));   // softplus (precise)
      }
      C[(size_t)row * ldc + col] = v;
    }
  }
}

// ------------- depthwise causal conv (width 4) + bias + SiLU ----------------
__global__ __launch_bounds__(256) void conv_silu_kernel(
    const float* __restrict__ xz,
    const float* __restrict__ cw,
    const float* __restrict__ cb,
    float* __restrict__ xc,
    short* __restrict__ xcb) {
  int idx = blockIdx.x * 256 + threadIdx.x;
  if (idx >= S_LEN * INNER) return;
  int s = idx / INNER;
  int c = idx - s * INNER;
  float acc = cb[c];
  #pragma unroll
  for (int k = 0; k < NCONV; ++k) {
    int t = s - (NCONV - 1) + k;
    if (t >= 0) acc += xz[(size_t)t * (2 * INNER) + c] * cw[k * INNER + c];
  }
  float v = acc / (1.f + fexp(-acc));
  xc[idx] = v;
  xcb[idx] = f2bf(v);
}

// ---------------- chunk-parallel SSM scan (3 passes) ------------------------
// v2: one thread per d-channel; all 16 l-states in registers; B/C rows staged
// in LDS (broadcast reads); delta/xc/z loads fully coalesced; no shuffles.

__global__ __launch_bounds__(256) void scan_pass1(
    const float* __restrict__ delta,
    const float* __restrict__ xp,
    const float* __restrict__ xc,
    const float* __restrict__ A_log,
    float* __restrict__ Aprod,
    float* __restrict__ Hend) {
  __shared__ float Bc[CHUNK][LSTATE];   // 2 KB
  const int tid = threadIdx.x;
  const int d = blockIdx.y * 256 + tid;
  const int c = blockIdx.x;
  const int s0 = c * CHUNK;
  for (int u = tid; u < CHUNK * LSTATE; u += 256) {
    int r = u >> 4, l = u & 15;
    Bc[r][l] = xp[(size_t)(s0 + r) * XPW + DRANK + l];
  }
  float a[LSTATE];
  {
    const float4* Ar = (const float4*)(A_log + (size_t)d * LSTATE);
    #pragma unroll
    for (int q = 0; q < 4; ++q) {
      float4 v = Ar[q];
      a[q * 4 + 0] = -fexp(v.x);
      a[q * 4 + 1] = -fexp(v.y);
      a[q * 4 + 2] = -fexp(v.z);
      a[q * 4 + 3] = -fexp(v.w);
    }
  }
  float h[LSTATE] = {}, ap[LSTATE];
  #pragma unroll
  for (int l = 0; l < LSTATE; ++l) ap[l] = 1.f;
  __syncthreads();
  const float* pd = delta + (size_t)s0 * INNER + d;
  const float* px = xc    + (size_t)s0 * INNER + d;
  for (int i = 0; i < CHUNK; ++i) {
    float dv = *pd, xcv = *px;
    pd += INNER; px += INNER;
    float sc = dv * xcv;
    #pragma unroll
    for (int l = 0; l < LSTATE; ++l) {
      float dA = fexp(dv * a[l]);
      h[l] = fmaf(dA, h[l], sc * Bc[i][l]);
      ap[l] *= dA;
    }
  }
  float4* Ap = (float4*)(Aprod + ((size_t)c * INNER + d) * LSTATE);
  float4* Hp = (float4*)(Hend  + ((size_t)c * INNER + d) * LSTATE);
  #pragma unroll
  for (int q = 0; q < 4; ++q) {
    Ap[q] = make_float4(ap[q * 4], ap[q * 4 + 1], ap[q * 4 + 2], ap[q * 4 + 3]);
    Hp[q] = make_float4(h[q * 4], h[q * 4 + 1], h[q * 4 + 2], h[q * 4 + 3]);
  }
}

__global__ __launch_bounds__(256) void scan_pass2(
    const float* __restrict__ Aprod, const float* __restrict__ Hend,
    float* __restrict__ Hin) {
  const int idx = blockIdx.x * 256 + threadIdx.x;
  float h = 0.f;
  for (int c = 0; c < NCHUNK; ++c) {
    size_t o = (size_t)c * INNER * LSTATE + idx;
    float ap = Aprod[o], he = Hend[o];
    Hin[o] = h;
    h = ap * h + he;
  }
}

__global__ __launch_bounds__(256) void scan_pass3(
    const float* __restrict__ delta,
    const float* __restrict__ xp,
    const float* __restrict__ xc,
    const float* __restrict__ xz,
    const float* __restrict__ A_log,
    const float* __restrict__ Dvec,
    const float* __restrict__ Hin,
    short* __restrict__ ybf) {        // [S, INNER] bf16 (feeds gemm_bf16)
  __shared__ float Bc[CHUNK][LSTATE];
  __shared__ float Cc[CHUNK][LSTATE];
  const int tid = threadIdx.x;
  const int d = blockIdx.y * 256 + tid;
  const int c = blockIdx.x;
  const int s0 = c * CHUNK;
  for (int u = tid; u < CHUNK * LSTATE; u += 256) {
    int r = u >> 4, l = u & 15;
    size_t base = (size_t)(s0 + r) * XPW + DRANK;
    Bc[r][l] = xp[base + l];
    Cc[r][l] = xp[base + LSTATE + l];
  }
  float a[LSTATE], h[LSTATE];
  {
    const float4* Ar = (const float4*)(A_log + (size_t)d * LSTATE);
    #pragma unroll
    for (int q = 0; q < 4; ++q) {
      float4 v = Ar[q];
      a[q * 4 + 0] = -fexp(v.x);
      a[q * 4 + 1] = -fexp(v.y);
      a[q * 4 + 2] = -fexp(v.z);
      a[q * 4 + 3] = -fexp(v.w);
    }
    const float4* Hi = (const float4*)(Hin + ((size_t)c * INNER + d) * LSTATE);
    #pragma unroll
    for (int q = 0; q < 4; ++q) {
      float4 v = Hi[q];
      h[q * 4 + 0] = v.x; h[q * 4 + 1] = v.y;
      h[q * 4 + 2] = v.z; h[q * 4 + 3] = v.w;
    }
  }
  const float Dd = Dvec[d];
  __syncthreads();
  const float* pd = delta + (size_t)s0 * INNER + d;
  const float* px = xc    + (size_t)s0 * INNER + d;
  const float* pz = xz + (size_t)s0 * (2 * INNER) + INNER + d;
  short* py = ybf + (size_t)s0 * INNER + d;
  for (int i = 0; i < CHUNK; ++i) {
    float dv = *pd, xcv = *px, zv = *pz;
    pd += INNER; px += INNER; pz += 2 * INNER;
    float sc = dv * xcv;
    float contrib = 0.f;
    #pragma unroll
    for (int l = 0; l < LSTATE; ++l) {
      float dA = fexp(dv * a[l]);
      h[l] = fmaf(dA, h[l], sc * Bc[i][l]);
      contrib = fmaf(h[l], Cc[i][l], contrib);
    }
    float silu_z = zv / (1.f + fexp(-zv));
    *py = f2bf(fmaf(xcv, Dd, contrib) * silu_z);
    py += INNER;
  }
}

extern "C" void kernel_launch(void* const* d_in, const int* in_sizes, int n_in,
                              void* d_out, int out_size, void* d_ws, size_t ws_size,
                              hipStream_t stream) {
  const float* x      = (const float*)d_in[0];   // [S, HID]
  const float* W_in   = (const float*)d_in[1];   // [HID, 2*INNER]
  const float* conv_w = (const float*)d_in[2];   // [4,1,INNER]
  const float* conv_b = (const float*)d_in[3];   // [INNER]
  const float* W_x    = (const float*)d_in[4];   // [INNER, 96]
  const float* W_delta= (const float*)d_in[5];   // [DRANK, INNER]
  const float* b_delta= (const float*)d_in[6];   // [INNER]
  const float* A_log  = (const float*)d_in[7];   // [INNER, L]
  const float* Dvec   = (const float*)d_in[8];   // [INNER]
  const float* W_out  = (const float*)d_in[9];   // [INNER, HID]
  float* out = (float*)d_out;

  float* ws    = (float*)d_ws;
  float* xz    = ws;                               // S * 2*INNER
  float* xc    = xz + (size_t)S_LEN * 2 * INNER;   // S * INNER
  float* xp    = xc + (size_t)S_LEN * INNER;       // S * XPW
  float* delta = xp + (size_t)S_LEN * XPW;         // S * INNER
  float* Aprod = delta + (size_t)S_LEN * INNER;    // NCHUNK * INNER * L
  float* Hend  = Aprod + (size_t)NCHUNK * INNER * LSTATE;
  float* Hin   = Hend  + (size_t)NCHUNK * INNER * LSTATE;
  short* xb    = (short*)(Hin + (size_t)NCHUNK * INNER * LSTATE); // S*HID bf16
  short* WinT  = xb + (size_t)S_LEN * HID;          // [2*INNER, HID] bf16
  short* WoutT = WinT + (size_t)(2 * INNER) * HID;  // [HID, INNER] bf16
  short* ybf   = WoutT + (size_t)HID * INNER;       // [S, INNER] bf16
  short* xcb   = ybf + (size_t)S_LEN * INNER;       // [S, INNER] bf16
  short* WxT   = xcb + (size_t)S_LEN * INNER;       // [XPAD, INNER] bf16
  float* xpPart = Aprod;   // K-split partials alias Aprod (dead until pass1)

  // 0. pre-passes
  cast_bf16_kernel<<<(S_LEN * HID / 4 + 255) / 256, 256, 0, stream>>>(
      x, xb, S_LEN * HID / 4);
  transpose_cast_kernel<<<dim3(2 * INNER / 32, HID / 32), 256, 0, stream>>>(
      W_in, WinT, HID, 2 * INNER);
  transpose_cast_kernel<<<dim3(HID / 32, INNER / 32), 256, 0, stream>>>(
      W_out, WoutT, INNER, HID);
  transpose_cast_kernel<<<dim3(XPAD / 32, INNER / 32), 256, 0, stream>>>(
      W_x, WxT, INNER, XPW);   // pad rows 96..127 zeroed

  // 1. xz = x @ W_in   (M=2048, N=4096, K=1024)  [bf16 MFMA]
  gemm_bf16<<<dim3(4096 / 128, 2048 / 128, 1), 256, 0, stream>>>(
      xb, HID, WinT, HID, xz, 2 * INNER, HID, 0);

  // 2. xc = silu(causal_depthwise_conv(xi) + conv_b)  (+ bf16 copy)
  conv_silu_kernel<<<(S_LEN * INNER + 255) / 256, 256, 0, stream>>>(
      xz, conv_w, conv_b, xc, xcb);

  // 3. xp = xc @ W_x   (M=2048, N=96, K=2048)  [bf16 MFMA, 4-way K-split]
  gemm_bf16<<<dim3(1, 2048 / 128, 4), 256, 0, stream>>>(
      xcb, INNER, WxT, INNER, xpPart, XPAD, INNER / 4,
      (size_t)S_LEN * XPAD);
  reduce_xp_kernel<<<(S_LEN * (XPW / 4) + 255) / 256, 256, 0, stream>>>(
      xpPart, xp);

  // 4. delta = softplus(xp[:, :64] @ W_delta + b_delta)
  gemm_tiled<1><<<dim3(2048 / 64, 2048 / 64), 256, 0, stream>>>(
      xp, XPW, W_delta, INNER, delta, INNER, S_LEN, INNER, DRANK, b_delta);

  // 5. chunk-parallel SSM scan -> ybf (fused +xc*D, *silu(z), bf16 cast)
  scan_pass1<<<dim3(NCHUNK, INNER / 256), 256, 0, stream>>>(
      delta, xp, xc, A_log, Aprod, Hend);
  scan_pass2<<<(INNER * LSTATE) / 256, 256, 0, stream>>>(Aprod, Hend, Hin);
  scan_pass3<<<dim3(NCHUNK, INNER / 256), 256, 0, stream>>>(
      delta, xp, xc, xz, A_log, Dvec, Hin, ybf);

  // 6. out = y @ W_out  (M=2048, N=1024, K=2048)  [bf16 MFMA]
  gemm_bf16<<<dim3(1024 / 128, 2048 / 128, 1), 256, 0, stream>>>(
      ybf, INNER, WoutT, INNER, out, HID, INNER, 0);
}

// Round 9
// 201.670 us; speedup vs baseline: 13.5309x; 1.1152x over previous
//
#include <hip/hip_runtime.h>
#include <hip/hip_bf16.h>
#include <math.h>

#define S_LEN 2048
#define HID   1024
#define INNER 2048
#define NCONV 4
#define LSTATE 16
#define DRANK 64
#define XPW   96   // DRANK + 2*LSTATE
#define CHUNK 32
#define NCHUNK (S_LEN / CHUNK)   // 64
#define XPAD  128  // padded N for the xp GEMM tile

typedef __attribute__((ext_vector_type(8))) short bf16x8;
typedef __attribute__((ext_vector_type(4))) float f32x4;

__device__ __forceinline__ short f2bf(float f) {
  union { __hip_bfloat16 h; short s; } u;
  u.h = __float2bfloat16(f);
  return u.s;
}

// fast exp: v_exp_f32-based (~1-2 ulp) — bf16 noise floor dominates anyway
__device__ __forceinline__ float fexp(float x) { return __expf(x); }

// async global->LDS, 16B per lane; lds dest = wave-uniform base + lane*16
#define GLDS(gp, lp) __builtin_amdgcn_global_load_lds(                         \
    (const __attribute__((address_space(1))) unsigned int*)(gp),               \
    (__attribute__((address_space(3))) unsigned int*)(lp), 16, 0, 0)

// ----------------------- fp32 -> bf16 cast (vectorized) ---------------------
__global__ __launch_bounds__(256) void cast_bf16_kernel(
    const float* __restrict__ in, short* __restrict__ out, int n4) {
  int i = blockIdx.x * 256 + threadIdx.x;
  if (i >= n4) return;
  const float4 v = ((const float4*)in)[i];
  short4 o;
  o.x = f2bf(v.x); o.y = f2bf(v.y); o.z = f2bf(v.z); o.w = f2bf(v.w);
  ((short4*)out)[i] = o;
}

// ------- transpose + cast: in[R][C] f32 -> out[Cpad][R] bf16 (pad rows = 0) -
__global__ __launch_bounds__(256) void transpose_cast_kernel(
    const float* __restrict__ in, short* __restrict__ out, int R, int C) {
  __shared__ float tile[32][33];
  const int bc = blockIdx.x * 32, br = blockIdx.y * 32;
  const int tx = threadIdx.x & 31, ty = threadIdx.x >> 5;   // 32 x 8
  #pragma unroll
  for (int i = 0; i < 32; i += 8)
    tile[ty + i][tx] = (bc + tx < C)
        ? in[(size_t)(br + ty + i) * C + bc + tx] : 0.f;
  __syncthreads();
  #pragma unroll
  for (int i = 0; i < 32; i += 8)
    out[(size_t)(bc + ty + i) * R + br + tx] = f2bf(tile[tx][ty + i]);
}

// --------------- bf16 MFMA GEMM: C[M,N] = A[M,K] @ Bt[N,K]^T ---------------
// 128x128 tile, BK=32, 4 waves (2x2), 2-phase pipeline:
//   STAGE(next, global_load_lds) -> compute(cur) -> syncthreads -> flip.
// LDS linear [128][32] shorts; 16B-slot XOR swizzle sigma = slot ^ ((row>>1)&3)
// applied on the GLOBAL source and the ds_read side (involution, rule #21);
// fragment reads then land each bank-start exactly 2x -> conflict-free (m136).
#define BK 32
__global__ __launch_bounds__(256) void gemm_bf16(
    const short* __restrict__ A,  int lda,    // [M,K] bf16 row-major
    const short* __restrict__ Bt, int ldb,    // [N,K] bf16 row-major
    float* __restrict__ C, int ldc,
    int kPerSplit, size_t cSliceStride) {
  __shared__ short As[2][128 * BK];
  __shared__ short Bs[2][128 * BK];
  const int tid  = threadIdx.x;
  const int lane = tid & 63;
  const int wave = tid >> 6;
  const int bm = blockIdx.y * 128;
  const int bn = blockIdx.x * 128;
  const int wm = (wave & 1) * 64;
  const int wn = (wave >> 1) * 64;
  const int fr = lane & 15;
  const int fq = lane >> 4;
  const int kbeg = blockIdx.z * kPerSplit;
  const int nIter = kPerSplit / BK;
  float* Cw = C + (size_t)blockIdx.z * cSliceStride;

  // staging geometry: wave covers rows [wave*32, wave*32+32) via 2 calls of 16
  const int rs0 = wave * 32 + (lane >> 2);        // call-0 row
  const int rs1 = rs0 + 16;                       // call-1 row
  const int sg0 = (lane & 3) ^ ((rs0 >> 1) & 3);  // source 16B chunk (swz)
  const int sg1 = (lane & 3) ^ ((rs1 >> 1) & 3);
  const short* gA0 = A  + (size_t)(bm + rs0) * lda + kbeg + sg0 * 8;
  const short* gA1 = A  + (size_t)(bm + rs1) * lda + kbeg + sg1 * 8;
  const short* gB0 = Bt + (size_t)(bn + rs0) * ldb + kbeg + sg0 * 8;
  const short* gB1 = Bt + (size_t)(bn + rs1) * ldb + kbeg + sg1 * 8;
  const int ldsR0 = (wave * 32) * BK;             // shorts
  const int ldsR1 = (wave * 32 + 16) * BK;

  f32x4 acc[4][4] = {};

  // prologue: stage tile 0 into buffer 0
  GLDS(gA0, &As[0][ldsR0]);
  GLDS(gA1, &As[0][ldsR1]);
  GLDS(gB0, &Bs[0][ldsR0]);
  GLDS(gB1, &Bs[0][ldsR1]);
  __syncthreads();   // drains vmcnt(0)

  const int sl = (fq ^ ((fr >> 1) & 3)) * 8;      // read-side swizzled slot
  int cur = 0;
  for (int t = 0; t < nIter; ++t) {
    if (t + 1 < nIter) {                          // stage next tile (async)
      const int ko = (t + 1) * BK;
      GLDS(gA0 + ko, &As[cur ^ 1][ldsR0]);
      GLDS(gA1 + ko, &As[cur ^ 1][ldsR1]);
      GLDS(gB0 + ko, &Bs[cur ^ 1][ldsR0]);
      GLDS(gB1 + ko, &Bs[cur ^ 1][ldsR1]);
    }
    bf16x8 af[4], bfv[4];
    #pragma unroll
    for (int mi = 0; mi < 4; ++mi)
      af[mi] = *(const bf16x8*)(&As[cur][(wm + mi * 16 + fr) * BK + sl]);
    #pragma unroll
    for (int ni = 0; ni < 4; ++ni)
      bfv[ni] = *(const bf16x8*)(&Bs[cur][(wn + ni * 16 + fr) * BK + sl]);
    #pragma unroll
    for (int mi = 0; mi < 4; ++mi)
      #pragma unroll
      for (int ni = 0; ni < 4; ++ni)
        acc[mi][ni] = __builtin_amdgcn_mfma_f32_16x16x32_bf16(
            af[mi], bfv[ni], acc[mi][ni], 0, 0, 0);
    __syncthreads();   // drains this iter's stage (vmcnt) + LDS reads
    cur ^= 1;
  }
  // C/D layout (m89): col = lane&15, row = (lane>>4)*4 + reg
  #pragma unroll
  for (int mi = 0; mi < 4; ++mi) {
    #pragma unroll
    for (int ni = 0; ni < 4; ++ni) {
      const int col = bn + wn + ni * 16 + fr;
      #pragma unroll
      for (int r = 0; r < 4; ++r) {
        const int row = bm + wm + mi * 16 + fq * 4 + r;
        Cw[(size_t)row * ldc + col] = acc[mi][ni][r];
      }
    }
  }
}

// ------- reduce 4 K-split partials [4][S][XPAD] -> xp [S][XPW] --------------
__global__ __launch_bounds__(256) void reduce_xp_kernel(
    const float* __restrict__ part, float* __restrict__ xp) {
  int i4 = blockIdx.x * 256 + threadIdx.x;
  if (i4 >= S_LEN * (XPW / 4)) return;
  int m = i4 / (XPW / 4);
  int n4 = i4 - m * (XPW / 4);
  const float4* p = (const float4*)part;
  const size_t rowv = (size_t)m * (XPAD / 4) + n4;
  const size_t slice = (size_t)S_LEN * (XPAD / 4);
  float4 a = p[rowv], b = p[rowv + slice], c = p[rowv + 2 * slice], d = p[rowv + 3 * slice];
  float4 o;
  o.x = (a.x + b.x) + (c.x + d.x);
  o.y = (a.y + b.y) + (c.y + d.y);
  o.z = (a.z + b.z) + (c.z + d.z);
  o.w = (a.w + b.w) + (c.w + d.w);
  ((float4*)xp)[i4] = o;
}

// ---------------- generic tiled fp32 GEMM (kept for delta GEMM) -------------
template<int EPI>
__global__ __launch_bounds__(256) void gemm_tiled(
    const float* __restrict__ A, int lda,
    const float* __restrict__ B, int ldb,
    float* __restrict__ C, int ldc,
    int M, int N, int K, const float* __restrict__ bias) {
  __shared__ float As[16][65];
  __shared__ float Bs[16][65];
  const int bm = blockIdx.y * 64;
  const int bn = blockIdx.x * 64;
  const int tid = threadIdx.x;
  const int tx = tid & 15;
  const int ty = tid >> 4;
  float acc[4][4] = {};
  for (int k0 = 0; k0 < K; k0 += 16) {
    #pragma unroll
    for (int i = tid; i < 64 * 16; i += 256) {
      int m = i >> 4, kk = i & 15;
      As[kk][m] = A[(size_t)(bm + m) * lda + k0 + kk];
    }
    #pragma unroll
    for (int i = tid; i < 16 * 64; i += 256) {
      int kk = i >> 6, n = i & 63;
      Bs[kk][n] = B[(size_t)(k0 + kk) * ldb + bn + n];
    }
    __syncthreads();
    #pragma unroll
    for (int kk = 0; kk < 16; ++kk) {
      float a[4], b[4];
      #pragma unroll
      for (int i = 0; i < 4; ++i) a[i] = As[kk][ty * 4 + i];
      #pragma unroll
      for (int j = 0; j < 4; ++j) b[j] = Bs[kk][tx * 4 + j];
      #pragma unroll
      for (int i = 0; i < 4; ++i)
        #pragma unroll
        for (int j = 0; j < 4; ++j)
          acc[i][j] += a[i] * b[j];
    }
    __syncthreads();
  }
  #pragma unroll
  for (int i = 0; i < 4; ++i) {
    #pragma unroll
    for (int j = 0; j < 4; ++j) {
      int row = bm + ty * 4 + i;
      int col = bn + tx * 4 + j;
      float v = acc[i][j];
      if (EPI == 1) {
        v += bias[col];
        v = fmaxf(v, 0.f) + log1pf(expf(-fabsf(v)));   // softplus (precise)
      }
      C[(size_t)row * ldc + col] = v;
    }
  }
}

// ------------- depthwise causal conv (width 4) + bias + SiLU ----------------
__global__ __launch_bounds__(256) void conv_silu_kernel(
    const float* __restrict__ xz,
    const float* __restrict__ cw,
    const float* __restrict__ cb,
    float* __restrict__ xc,
    short* __restrict__ xcb) {
  int idx = blockIdx.x * 256 + threadIdx.x;
  if (idx >= S_LEN * INNER) return;
  int s = idx / INNER;
  int c = idx - s * INNER;
  float acc = cb[c];
  #pragma unroll
  for (int k = 0; k < NCONV; ++k) {
    int t = s - (NCONV - 1) + k;
    if (t >= 0) acc += xz[(size_t)t * (2 * INNER) + c] * cw[k * INNER + c];
  }
  float v = acc / (1.f + fexp(-acc));
  xc[idx] = v;
  xcb[idx] = f2bf(v);
}

// ---------------- chunk-parallel SSM scan (3 passes) ------------------------
// one thread per d-channel; 16 l-states in registers; B/C staged in LDS.

__global__ __launch_bounds__(256) void scan_pass1(
    const float* __restrict__ delta,
    const float* __restrict__ xp,
    const float* __restrict__ xc,
    const float* __restrict__ A_log,
    float* __restrict__ Aprod,
    float* __restrict__ Hend) {
  __shared__ float Bc[CHUNK][LSTATE];   // 2 KB
  const int tid = threadIdx.x;
  const int d = blockIdx.y * 256 + tid;
  const int c = blockIdx.x;
  const int s0 = c * CHUNK;
  for (int u = tid; u < CHUNK * LSTATE; u += 256) {
    int r = u >> 4, l = u & 15;
    Bc[r][l] = xp[(size_t)(s0 + r) * XPW + DRANK + l];
  }
  float a[LSTATE];
  {
    const float4* Ar = (const float4*)(A_log + (size_t)d * LSTATE);
    #pragma unroll
    for (int q = 0; q < 4; ++q) {
      float4 v = Ar[q];
      a[q * 4 + 0] = -fexp(v.x);
      a[q * 4 + 1] = -fexp(v.y);
      a[q * 4 + 2] = -fexp(v.z);
      a[q * 4 + 3] = -fexp(v.w);
    }
  }
  float h[LSTATE] = {}, ap[LSTATE];
  #pragma unroll
  for (int l = 0; l < LSTATE; ++l) ap[l] = 1.f;
  __syncthreads();
  const float* pd = delta + (size_t)s0 * INNER + d;
  const float* px = xc    + (size_t)s0 * INNER + d;
  for (int i = 0; i < CHUNK; ++i) {
    float dv = *pd, xcv = *px;
    pd += INNER; px += INNER;
    float sc = dv * xcv;
    #pragma unroll
    for (int l = 0; l < LSTATE; ++l) {
      float dA = fexp(dv * a[l]);
      h[l] = fmaf(dA, h[l], sc * Bc[i][l]);
      ap[l] *= dA;
    }
  }
  float4* Ap = (float4*)(Aprod + ((size_t)c * INNER + d) * LSTATE);
  float4* Hp = (float4*)(Hend  + ((size_t)c * INNER + d) * LSTATE);
  #pragma unroll
  for (int q = 0; q < 4; ++q) {
    Ap[q] = make_float4(ap[q * 4], ap[q * 4 + 1], ap[q * 4 + 2], ap[q * 4 + 3]);
    Hp[q] = make_float4(h[q * 4], h[q * 4 + 1], h[q * 4 + 2], h[q * 4 + 3]);
  }
}

__global__ __launch_bounds__(256) void scan_pass2(
    const float* __restrict__ Aprod, const float* __restrict__ Hend,
    float* __restrict__ Hin) {
  const int idx = blockIdx.x * 256 + threadIdx.x;
  float h = 0.f;
  for (int c = 0; c < NCHUNK; ++c) {
    size_t o = (size_t)c * INNER * LSTATE + idx;
    float ap = Aprod[o], he = Hend[o];
    Hin[o] = h;
    h = ap * h + he;
  }
}

__global__ __launch_bounds__(256) void scan_pass3(
    const float* __restrict__ delta,
    const float* __restrict__ xp,
    const float* __restrict__ xc,
    const float* __restrict__ xz,
    const float* __restrict__ A_log,
    const float* __restrict__ Dvec,
    const float* __restrict__ Hin,
    short* __restrict__ ybf) {        // [S, INNER] bf16 (feeds gemm_bf16)
  __shared__ float Bc[CHUNK][LSTATE];
  __shared__ float Cc[CHUNK][LSTATE];
  const int tid = threadIdx.x;
  const int d = blockIdx.y * 256 + tid;
  const int c = blockIdx.x;
  const int s0 = c * CHUNK;
  for (int u = tid; u < CHUNK * LSTATE; u += 256) {
    int r = u >> 4, l = u & 15;
    size_t base = (size_t)(s0 + r) * XPW + DRANK;
    Bc[r][l] = xp[base + l];
    Cc[r][l] = xp[base + LSTATE + l];
  }
  float a[LSTATE], h[LSTATE];
  {
    const float4* Ar = (const float4*)(A_log + (size_t)d * LSTATE);
    #pragma unroll
    for (int q = 0; q < 4; ++q) {
      float4 v = Ar[q];
      a[q * 4 + 0] = -fexp(v.x);
      a[q * 4 + 1] = -fexp(v.y);
      a[q * 4 + 2] = -fexp(v.z);
      a[q * 4 + 3] = -fexp(v.w);
    }
    const float4* Hi = (const float4*)(Hin + ((size_t)c * INNER + d) * LSTATE);
    #pragma unroll
    for (int q = 0; q < 4; ++q) {
      float4 v = Hi[q];
      h[q * 4 + 0] = v.x; h[q * 4 + 1] = v.y;
      h[q * 4 + 2] = v.z; h[q * 4 + 3] = v.w;
    }
  }
  const float Dd = Dvec[d];
  __syncthreads();
  const float* pd = delta + (size_t)s0 * INNER + d;
  const float* px = xc    + (size_t)s0 * INNER + d;
  const float* pz = xz + (size_t)s0 * (2 * INNER) + INNER + d;
  short* py = ybf + (size_t)s0 * INNER + d;
  for (int i = 0; i < CHUNK; ++i) {
    float dv = *pd, xcv = *px, zv = *pz;
    pd += INNER; px += INNER; pz += 2 * INNER;
    float sc = dv * xcv;
    float contrib = 0.f;
    #pragma unroll
    for (int l = 0; l < LSTATE; ++l) {
      float dA = fexp(dv * a[l]);
      h[l] = fmaf(dA, h[l], sc * Bc[i][l]);
      contrib = fmaf(h[l], Cc[i][l], contrib);
    }
    float silu_z = zv / (1.f + fexp(-zv));
    *py = f2bf(fmaf(xcv, Dd, contrib) * silu_z);
    py += INNER;
  }
}

extern "C" void kernel_launch(void* const* d_in, const int* in_sizes, int n_in,
                              void* d_out, int out_size, void* d_ws, size_t ws_size,
                              hipStream_t stream) {
  const float* x      = (const float*)d_in[0];   // [S, HID]
  const float* W_in   = (const float*)d_in[1];   // [HID, 2*INNER]
  const float* conv_w = (const float*)d_in[2];   // [4,1,INNER]
  const float* conv_b = (const float*)d_in[3];   // [INNER]
  const float* W_x    = (const float*)d_in[4];   // [INNER, 96]
  const float* W_delta= (const float*)d_in[5];   // [DRANK, INNER]
  const float* b_delta= (const float*)d_in[6];   // [INNER]
  const float* A_log  = (const float*)d_in[7];   // [INNER, L]
  const float* Dvec   = (const float*)d_in[8];   // [INNER]
  const float* W_out  = (const float*)d_in[9];   // [INNER, HID]
  float* out = (float*)d_out;

  float* ws    = (float*)d_ws;
  float* xz    = ws;                               // S * 2*INNER
  float* xc    = xz + (size_t)S_LEN * 2 * INNER;   // S * INNER
  float* xp    = xc + (size_t)S_LEN * INNER;       // S * XPW
  float* delta = xp + (size_t)S_LEN * XPW;         // S * INNER
  float* Aprod = delta + (size_t)S_LEN * INNER;    // NCHUNK * INNER * L
  float* Hend  = Aprod + (size_t)NCHUNK * INNER * LSTATE;
  float* Hin   = Hend  + (size_t)NCHUNK * INNER * LSTATE;
  short* xb    = (short*)(Hin + (size_t)NCHUNK * INNER * LSTATE); // S*HID bf16
  short* WinT  = xb + (size_t)S_LEN * HID;          // [2*INNER, HID] bf16
  short* WoutT = WinT + (size_t)(2 * INNER) * HID;  // [HID, INNER] bf16
  short* ybf   = WoutT + (size_t)HID * INNER;       // [S, INNER] bf16
  short* xcb   = ybf + (size_t)S_LEN * INNER;       // [S, INNER] bf16
  short* WxT   = xcb + (size_t)S_LEN * INNER;       // [XPAD, INNER] bf16
  float* xpPart = Aprod;   // K-split partials alias Aprod (dead until pass1)

  // 0. pre-passes
  cast_bf16_kernel<<<(S_LEN * HID / 4 + 255) / 256, 256, 0, stream>>>(
      x, xb, S_LEN * HID / 4);
  transpose_cast_kernel<<<dim3(2 * INNER / 32, HID / 32), 256, 0, stream>>>(
      W_in, WinT, HID, 2 * INNER);
  transpose_cast_kernel<<<dim3(HID / 32, INNER / 32), 256, 0, stream>>>(
      W_out, WoutT, INNER, HID);
  transpose_cast_kernel<<<dim3(XPAD / 32, INNER / 32), 256, 0, stream>>>(
      W_x, WxT, INNER, XPW);   // pad rows 96..127 zeroed

  // 1. xz = x @ W_in   (M=2048, N=4096, K=1024)  [bf16 MFMA]
  gemm_bf16<<<dim3(4096 / 128, 2048 / 128, 1), 256, 0, stream>>>(
      xb, HID, WinT, HID, xz, 2 * INNER, HID, 0);

  // 2. xc = silu(causal_depthwise_conv(xi) + conv_b)  (+ bf16 copy)
  conv_silu_kernel<<<(S_LEN * INNER + 255) / 256, 256, 0, stream>>>(
      xz, conv_w, conv_b, xc, xcb);

  // 3. xp = xc @ W_x   (M=2048, N=96, K=2048)  [bf16 MFMA, 4-way K-split]
  gemm_bf16<<<dim3(1, 2048 / 128, 4), 256, 0, stream>>>(
      xcb, INNER, WxT, INNER, xpPart, XPAD, INNER / 4,
      (size_t)S_LEN * XPAD);
  reduce_xp_kernel<<<(S_LEN * (XPW / 4) + 255) / 256, 256, 0, stream>>>(
      xpPart, xp);

  // 4. delta = softplus(xp[:, :64] @ W_delta + b_delta)
  gemm_tiled<1><<<dim3(2048 / 64, 2048 / 64), 256, 0, stream>>>(
      xp, XPW, W_delta, INNER, delta, INNER, S_LEN, INNER, DRANK, b_delta);

  // 5. chunk-parallel SSM scan -> ybf (fused +xc*D, *silu(z), bf16 cast)
  scan_pass1<<<dim3(NCHUNK, INNER / 256), 256, 0, stream>>>(
      delta, xp, xc, A_log, Aprod, Hend);
  scan_pass2<<<(INNER * LSTATE) / 256, 256, 0, stream>>>(Aprod, Hend, Hin);
  scan_pass3<<<dim3(NCHUNK, INNER / 256), 256, 0, stream>>>(
      delta, xp, xc, xz, A_log, Dvec, Hin, ybf);

  // 6. out = y @ W_out  (M=2048, N=1024, K=2048)  [bf16 MFMA]
  gemm_bf16<<<dim3(1024 / 128, 2048 / 128, 1), 256, 0, stream>>>(
      ybf, INNER, WoutT, INNER, out, HID, INNER, 0);
}

// Round 10
// 189.056 us; speedup vs baseline: 14.4337x; 1.0667x over previous
//
#include <hip/hip_runtime.h>
#include <hip/hip_bf16.h>
#include <math.h>

#define S_LEN 2048
#define HID   1024
#define INNER 2048
#define NCONV 4
#define LSTATE 16
#define DRANK 64
#define XPW   96   // DRANK + 2*LSTATE
#define CHUNK 32
#define NCHUNK (S_LEN / CHUNK)   // 64
#define XPAD  128  // padded N for the xp GEMM tile
#define XPSPLIT 8  // K-split for the xp GEMM

typedef __attribute__((ext_vector_type(8))) short bf16x8;
typedef __attribute__((ext_vector_type(4))) float f32x4;

__device__ __forceinline__ short f2bf(float f) {
  union { __hip_bfloat16 h; short s; } u;
  u.h = __float2bfloat16(f);
  return u.s;
}

// fast exp: v_exp_f32-based (~1-2 ulp) — bf16 noise floor dominates anyway
__device__ __forceinline__ float fexp(float x) { return __expf(x); }

// async global->LDS, 16B per lane; lds dest = wave-uniform base + lane*16
#define GLDS(gp, lp) __builtin_amdgcn_global_load_lds(                         \
    (const __attribute__((address_space(1))) unsigned int*)(gp),               \
    (__attribute__((address_space(3))) unsigned int*)(lp), 16, 0, 0)

// ----------------------- fp32 -> bf16 cast (vectorized) ---------------------
__global__ __launch_bounds__(256) void cast_bf16_kernel(
    const float* __restrict__ in, short* __restrict__ out, int n4) {
  int i = blockIdx.x * 256 + threadIdx.x;
  if (i >= n4) return;
  const float4 v = ((const float4*)in)[i];
  short4 o;
  o.x = f2bf(v.x); o.y = f2bf(v.y); o.z = f2bf(v.z); o.w = f2bf(v.w);
  ((short4*)out)[i] = o;
}

// ------- transpose + cast: in[R][C] f32 -> out[Cpad][R] bf16 (pad rows = 0) -
__global__ __launch_bounds__(256) void transpose_cast_kernel(
    const float* __restrict__ in, short* __restrict__ out, int R, int C) {
  __shared__ float tile[32][33];
  const int bc = blockIdx.x * 32, br = blockIdx.y * 32;
  const int tx = threadIdx.x & 31, ty = threadIdx.x >> 5;   // 32 x 8
  #pragma unroll
  for (int i = 0; i < 32; i += 8)
    tile[ty + i][tx] = (bc + tx < C)
        ? in[(size_t)(br + ty + i) * C + bc + tx] : 0.f;
  __syncthreads();
  #pragma unroll
  for (int i = 0; i < 32; i += 8)
    out[(size_t)(bc + ty + i) * R + br + tx] = f2bf(tile[tx][ty + i]);
}

// --------------- bf16 MFMA GEMM: C[M,N] = A[M,K] @ Bt[N,K]^T ---------------
// 128x128 tile, BK=32, 4 waves (2x2). 3-buffer pipeline, counted vmcnt (T4):
//   prologue: stage(0), stage(1)
//   iter t:  s_waitcnt vmcnt(4)   [tile t landed; only stage(t+1) may fly]
//            s_barrier            [raw; our own waitcnt discipline]
//            stage(t+2) -> buf[(t+2)%3]
//            ds_read buf[t%3] + MFMA
// Requires nIter >= 2. LDS 16B-slot XOR swizzle sigma = slot ^ ((row>>1)&3)
// on global source + read side (involution, rule #21) -> 0 bank conflicts.
#define BK 32
__global__ __launch_bounds__(256) void gemm_bf16(
    const short* __restrict__ A,  int lda,    // [M,K] bf16 row-major
    const short* __restrict__ Bt, int ldb,    // [N,K] bf16 row-major
    float* __restrict__ C, int ldc,
    int kPerSplit, size_t cSliceStride) {
  __shared__ short As[3][128 * BK];
  __shared__ short Bs[3][128 * BK];
  const int tid  = threadIdx.x;
  const int lane = tid & 63;
  const int wave = tid >> 6;
  const int bm = blockIdx.y * 128;
  const int bn = blockIdx.x * 128;
  const int wm = (wave & 1) * 64;
  const int wn = (wave >> 1) * 64;
  const int fr = lane & 15;
  const int fq = lane >> 4;
  const int kbeg = blockIdx.z * kPerSplit;
  const int nIter = kPerSplit / BK;
  float* Cw = C + (size_t)blockIdx.z * cSliceStride;

  // staging geometry: wave covers rows [wave*32, wave*32+32) via 2 calls of 16
  const int rs0 = wave * 32 + (lane >> 2);        // call-0 row
  const int rs1 = rs0 + 16;                       // call-1 row
  const int sg0 = (lane & 3) ^ ((rs0 >> 1) & 3);  // source 16B chunk (swz)
  const int sg1 = (lane & 3) ^ ((rs1 >> 1) & 3);
  const short* gA0 = A  + (size_t)(bm + rs0) * lda + kbeg + sg0 * 8;
  const short* gA1 = A  + (size_t)(bm + rs1) * lda + kbeg + sg1 * 8;
  const short* gB0 = Bt + (size_t)(bn + rs0) * ldb + kbeg + sg0 * 8;
  const short* gB1 = Bt + (size_t)(bn + rs1) * ldb + kbeg + sg1 * 8;
  const int ldsR0 = (wave * 32) * BK;             // shorts
  const int ldsR1 = (wave * 32 + 16) * BK;

  f32x4 acc[4][4] = {};

  // prologue: stage tiles 0 and 1
  GLDS(gA0, &As[0][ldsR0]);
  GLDS(gA1, &As[0][ldsR1]);
  GLDS(gB0, &Bs[0][ldsR0]);
  GLDS(gB1, &Bs[0][ldsR1]);
  GLDS(gA0 + BK, &As[1][ldsR0]);
  GLDS(gA1 + BK, &As[1][ldsR1]);
  GLDS(gB0 + BK, &Bs[1][ldsR0]);
  GLDS(gB1 + BK, &Bs[1][ldsR1]);

  const int sl = (fq ^ ((fr >> 1) & 3)) * 8;      // read-side swizzled slot
  for (int t = 0; t < nIter; ++t) {
    if (t + 1 < nIter) asm volatile("s_waitcnt vmcnt(4)" ::: "memory");
    else               asm volatile("s_waitcnt vmcnt(0)" ::: "memory");
    asm volatile("s_barrier" ::: "memory");
    if (t + 2 < nIter) {                          // stage tile t+2 (async)
      const int ko = (t + 2) * BK;
      const int w = (t + 2) % 3;
      GLDS(gA0 + ko, &As[w][ldsR0]);
      GLDS(gA1 + ko, &As[w][ldsR1]);
      GLDS(gB0 + ko, &Bs[w][ldsR0]);
      GLDS(gB1 + ko, &Bs[w][ldsR1]);
    }
    const int r = t % 3;
    bf16x8 af[4], bfv[4];
    #pragma unroll
    for (int mi = 0; mi < 4; ++mi)
      af[mi] = *(const bf16x8*)(&As[r][(wm + mi * 16 + fr) * BK + sl]);
    #pragma unroll
    for (int ni = 0; ni < 4; ++ni)
      bfv[ni] = *(const bf16x8*)(&Bs[r][(wn + ni * 16 + fr) * BK + sl]);
    #pragma unroll
    for (int mi = 0; mi < 4; ++mi)
      #pragma unroll
      for (int ni = 0; ni < 4; ++ni)
        acc[mi][ni] = __builtin_amdgcn_mfma_f32_16x16x32_bf16(
            af[mi], bfv[ni], acc[mi][ni], 0, 0, 0);
  }
  // C/D layout (m89): col = lane&15, row = (lane>>4)*4 + reg
  #pragma unroll
  for (int mi = 0; mi < 4; ++mi) {
    #pragma unroll
    for (int ni = 0; ni < 4; ++ni) {
      const int col = bn + wn + ni * 16 + fr;
      #pragma unroll
      for (int r = 0; r < 4; ++r) {
        const int row = bm + wm + mi * 16 + fq * 4 + r;
        Cw[(size_t)row * ldc + col] = acc[mi][ni][r];
      }
    }
  }
}

// ------- reduce XPSPLIT K-split partials [Z][S][XPAD] -> xp [S][XPW] --------
__global__ __launch_bounds__(256) void reduce_xp_kernel(
    const float* __restrict__ part, float* __restrict__ xp) {
  int i4 = blockIdx.x * 256 + threadIdx.x;
  if (i4 >= S_LEN * (XPW / 4)) return;
  int m = i4 / (XPW / 4);
  int n4 = i4 - m * (XPW / 4);
  const float4* p = (const float4*)part;
  const size_t rowv = (size_t)m * (XPAD / 4) + n4;
  const size_t slice = (size_t)S_LEN * (XPAD / 4);
  float4 o = p[rowv];
  #pragma unroll
  for (int s = 1; s < XPSPLIT; ++s) {   // fixed order: deterministic
    float4 v = p[rowv + s * slice];
    o.x += v.x; o.y += v.y; o.z += v.z; o.w += v.w;
  }
  ((float4*)xp)[i4] = o;
}

// ------------- reduce 2 K-split partials [2][S][HID] -> out ----------------
__global__ __launch_bounds__(256) void reduce_out_kernel(
    const float* __restrict__ part, float* __restrict__ out) {
  int i4 = blockIdx.x * 256 + threadIdx.x;
  if (i4 >= S_LEN * (HID / 4)) return;
  const float4* p = (const float4*)part;
  const size_t slice = (size_t)S_LEN * (HID / 4);
  float4 a = p[i4], b = p[i4 + slice];
  float4 o;
  o.x = a.x + b.x; o.y = a.y + b.y; o.z = a.z + b.z; o.w = a.w + b.w;
  ((float4*)out)[i4] = o;
}

// ---------------- generic tiled fp32 GEMM (kept for delta GEMM) -------------
template<int EPI>
__global__ __launch_bounds__(256) void gemm_tiled(
    const float* __restrict__ A, int lda,
    const float* __restrict__ B, int ldb,
    float* __restrict__ C, int ldc,
    int M, int N, int K, const float* __restrict__ bias) {
  __shared__ float As[16][65];
  __shared__ float Bs[16][65];
  const int bm = blockIdx.y * 64;
  const int bn = blockIdx.x * 64;
  const int tid = threadIdx.x;
  const int tx = tid & 15;
  const int ty = tid >> 4;
  float acc[4][4] = {};
  for (int k0 = 0; k0 < K; k0 += 16) {
    #pragma unroll
    for (int i = tid; i < 64 * 16; i += 256) {
      int m = i >> 4, kk = i & 15;
      As[kk][m] = A[(size_t)(bm + m) * lda + k0 + kk];
    }
    #pragma unroll
    for (int i = tid; i < 16 * 64; i += 256) {
      int kk = i >> 6, n = i & 63;
      Bs[kk][n] = B[(size_t)(k0 + kk) * ldb + bn + n];
    }
    __syncthreads();
    #pragma unroll
    for (int kk = 0; kk < 16; ++kk) {
      float a[4], b[4];
      #pragma unroll
      for (int i = 0; i < 4; ++i) a[i] = As[kk][ty * 4 + i];
      #pragma unroll
      for (int j = 0; j < 4; ++j) b[j] = Bs[kk][tx * 4 + j];
      #pragma unroll
      for (int i = 0; i < 4; ++i)
        #pragma unroll
        for (int j = 0; j < 4; ++j)
          acc[i][j] += a[i] * b[j];
    }
    __syncthreads();
  }
  #pragma unroll
  for (int i = 0; i < 4; ++i) {
    #pragma unroll
    for (int j = 0; j < 4; ++j) {
      int row = bm + ty * 4 + i;
      int col = bn + tx * 4 + j;
      float v = acc[i][j];
      if (EPI == 1) {
        v += bias[col];
        v = fmaxf(v, 0.f) + log1pf(expf(-fabsf(v)));   // softplus (precise)
      }
      C[(size_t)row * ldc + col] = v;
    }
  }
}

// ------------- depthwise causal conv (width 4) + bias + SiLU ----------------
__global__ __launch_bounds__(256) void conv_silu_kernel(
    const float* __restrict__ xz,
    const float* __restrict__ cw,
    const float* __restrict__ cb,
    float* __restrict__ xc,
    short* __restrict__ xcb) {
  int idx = blockIdx.x * 256 + threadIdx.x;
  if (idx >= S_LEN * INNER) return;
  int s = idx / INNER;
  int c = idx - s * INNER;
  float acc = cb[c];
  #pragma unroll
  for (int k = 0; k < NCONV; ++k) {
    int t = s - (NCONV - 1) + k;
    if (t >= 0) acc += xz[(size_t)t * (2 * INNER) + c] * cw[k * INNER + c];
  }
  float v = acc / (1.f + fexp(-acc));
  xc[idx] = v;
  xcb[idx] = f2bf(v);
}

// ---------------- chunk-parallel SSM scan (3 passes) ------------------------
// one thread per d-channel; 16 l-states in registers; B/C staged in LDS.

__global__ __launch_bounds__(256) void scan_pass1(
    const float* __restrict__ delta,
    const float* __restrict__ xp,
    const float* __restrict__ xc,
    const float* __restrict__ A_log,
    float* __restrict__ Aprod,
    float* __restrict__ Hend) {
  __shared__ float Bc[CHUNK][LSTATE];   // 2 KB
  const int tid = threadIdx.x;
  const int d = blockIdx.y * 256 + tid;
  const int c = blockIdx.x;
  const int s0 = c * CHUNK;
  for (int u = tid; u < CHUNK * LSTATE; u += 256) {
    int r = u >> 4, l = u & 15;
    Bc[r][l] = xp[(size_t)(s0 + r) * XPW + DRANK + l];
  }
  float a[LSTATE];
  {
    const float4* Ar = (const float4*)(A_log + (size_t)d * LSTATE);
    #pragma unroll
    for (int q = 0; q < 4; ++q) {
      float4 v = Ar[q];
      a[q * 4 + 0] = -fexp(v.x);
      a[q * 4 + 1] = -fexp(v.y);
      a[q * 4 + 2] = -fexp(v.z);
      a[q * 4 + 3] = -fexp(v.w);
    }
  }
  float h[LSTATE] = {}, ap[LSTATE];
  #pragma unroll
  for (int l = 0; l < LSTATE; ++l) ap[l] = 1.f;
  __syncthreads();
  const float* pd = delta + (size_t)s0 * INNER + d;
  const float* px = xc    + (size_t)s0 * INNER + d;
  for (int i = 0; i < CHUNK; ++i) {
    float dv = *pd, xcv = *px;
    pd += INNER; px += INNER;
    float sc = dv * xcv;
    #pragma unroll
    for (int l = 0; l < LSTATE; ++l) {
      float dA = fexp(dv * a[l]);
      h[l] = fmaf(dA, h[l], sc * Bc[i][l]);
      ap[l] *= dA;
    }
  }
  float4* Ap = (float4*)(Aprod + ((size_t)c * INNER + d) * LSTATE);
  float4* Hp = (float4*)(Hend  + ((size_t)c * INNER + d) * LSTATE);
  #pragma unroll
  for (int q = 0; q < 4; ++q) {
    Ap[q] = make_float4(ap[q * 4], ap[q * 4 + 1], ap[q * 4 + 2], ap[q * 4 + 3]);
    Hp[q] = make_float4(h[q * 4], h[q * 4 + 1], h[q * 4 + 2], h[q * 4 + 3]);
  }
}

__global__ __launch_bounds__(256) void scan_pass2(
    const float* __restrict__ Aprod, const float* __restrict__ Hend,
    float* __restrict__ Hin) {
  const int idx = blockIdx.x * 256 + threadIdx.x;
  float h = 0.f;
  for (int c = 0; c < NCHUNK; ++c) {
    size_t o = (size_t)c * INNER * LSTATE + idx;
    float ap = Aprod[o], he = Hend[o];
    Hin[o] = h;
    h = ap * h + he;
  }
}

__global__ __launch_bounds__(256) void scan_pass3(
    const float* __restrict__ delta,
    const float* __restrict__ xp,
    const float* __restrict__ xc,
    const float* __restrict__ xz,
    const float* __restrict__ A_log,
    const float* __restrict__ Dvec,
    const float* __restrict__ Hin,
    short* __restrict__ ybf) {        // [S, INNER] bf16 (feeds gemm_bf16)
  __shared__ float Bc[CHUNK][LSTATE];
  __shared__ float Cc[CHUNK][LSTATE];
  const int tid = threadIdx.x;
  const int d = blockIdx.y * 256 + tid;
  const int c = blockIdx.x;
  const int s0 = c * CHUNK;
  for (int u = tid; u < CHUNK * LSTATE; u += 256) {
    int r = u >> 4, l = u & 15;
    size_t base = (size_t)(s0 + r) * XPW + DRANK;
    Bc[r][l] = xp[base + l];
    Cc[r][l] = xp[base + LSTATE + l];
  }
  float a[LSTATE], h[LSTATE];
  {
    const float4* Ar = (const float4*)(A_log + (size_t)d * LSTATE);
    #pragma unroll
    for (int q = 0; q < 4; ++q) {
      float4 v = Ar[q];
      a[q * 4 + 0] = -fexp(v.x);
      a[q * 4 + 1] = -fexp(v.y);
      a[q * 4 + 2] = -fexp(v.z);
      a[q * 4 + 3] = -fexp(v.w);
    }
    const float4* Hi = (const float4*)(Hin + ((size_t)c * INNER + d) * LSTATE);
    #pragma unroll
    for (int q = 0; q < 4; ++q) {
      float4 v = Hi[q];
      h[q * 4 + 0] = v.x; h[q * 4 + 1] = v.y;
      h[q * 4 + 2] = v.z; h[q * 4 + 3] = v.w;
    }
  }
  const float Dd = Dvec[d];
  __syncthreads();
  const float* pd = delta + (size_t)s0 * INNER + d;
  const float* px = xc    + (size_t)s0 * INNER + d;
  const float* pz = xz + (size_t)s0 * (2 * INNER) + INNER + d;
  short* py = ybf + (size_t)s0 * INNER + d;
  for (int i = 0; i < CHUNK; ++i) {
    float dv = *pd, xcv = *px, zv = *pz;
    pd += INNER; px += INNER; pz += 2 * INNER;
    float sc = dv * xcv;
    float contrib = 0.f;
    #pragma unroll
    for (int l = 0; l < LSTATE; ++l) {
      float dA = fexp(dv * a[l]);
      h[l] = fmaf(dA, h[l], sc * Bc[i][l]);
      contrib = fmaf(h[l], Cc[i][l], contrib);
    }
    float silu_z = zv / (1.f + fexp(-zv));
    *py = f2bf(fmaf(xcv, Dd, contrib) * silu_z);
    py += INNER;
  }
}

extern "C" void kernel_launch(void* const* d_in, const int* in_sizes, int n_in,
                              void* d_out, int out_size, void* d_ws, size_t ws_size,
                              hipStream_t stream) {
  const float* x      = (const float*)d_in[0];   // [S, HID]
  const float* W_in   = (const float*)d_in[1];   // [HID, 2*INNER]
  const float* conv_w = (const float*)d_in[2];   // [4,1,INNER]
  const float* conv_b = (const float*)d_in[3];   // [INNER]
  const float* W_x    = (const float*)d_in[4];   // [INNER, 96]
  const float* W_delta= (const float*)d_in[5];   // [DRANK, INNER]
  const float* b_delta= (const float*)d_in[6];   // [INNER]
  const float* A_log  = (const float*)d_in[7];   // [INNER, L]
  const float* Dvec   = (const float*)d_in[8];   // [INNER]
  const float* W_out  = (const float*)d_in[9];   // [INNER, HID]
  float* out = (float*)d_out;

  float* ws    = (float*)d_ws;
  float* xz    = ws;                               // S * 2*INNER
  float* xc    = xz + (size_t)S_LEN * 2 * INNER;   // S * INNER
  float* xp    = xc + (size_t)S_LEN * INNER;       // S * XPW
  float* delta = xp + (size_t)S_LEN * XPW;         // S * INNER
  float* Aprod = delta + (size_t)S_LEN * INNER;    // NCHUNK * INNER * L
  float* Hend  = Aprod + (size_t)NCHUNK * INNER * LSTATE;
  float* Hin   = Hend  + (size_t)NCHUNK * INNER * LSTATE;
  short* xb    = (short*)(Hin + (size_t)NCHUNK * INNER * LSTATE); // S*HID bf16
  short* WinT  = xb + (size_t)S_LEN * HID;          // [2*INNER, HID] bf16
  short* WoutT = WinT + (size_t)(2 * INNER) * HID;  // [HID, INNER] bf16
  short* ybf   = WoutT + (size_t)HID * INNER;       // [S, INNER] bf16
  short* xcb   = ybf + (size_t)S_LEN * INNER;       // [S, INNER] bf16
  short* WxT   = xcb + (size_t)S_LEN * INNER;       // [XPAD, INNER] bf16
  // K-split partials alias the Aprod..Hin region (24 MB, dead until pass1 /
  // dead after pass3): xp partials [8][S][XPAD]=8MB before the scan,
  // out partials [2][S][HID]=16MB after the scan.
  float* xpPart  = Aprod;
  float* outPart = Aprod;

  // 0. pre-passes
  cast_bf16_kernel<<<(S_LEN * HID / 4 + 255) / 256, 256, 0, stream>>>(
      x, xb, S_LEN * HID / 4);
  transpose_cast_kernel<<<dim3(2 * INNER / 32, HID / 32), 256, 0, stream>>>(
      W_in, WinT, HID, 2 * INNER);
  transpose_cast_kernel<<<dim3(HID / 32, INNER / 32), 256, 0, stream>>>(
      W_out, WoutT, INNER, HID);
  transpose_cast_kernel<<<dim3(XPAD / 32, INNER / 32), 256, 0, stream>>>(
      W_x, WxT, INNER, XPW);   // pad rows 96..127 zeroed

  // 1. xz = x @ W_in   (M=2048, N=4096, K=1024)  [bf16 MFMA, pipelined]
  gemm_bf16<<<dim3(4096 / 128, 2048 / 128, 1), 256, 0, stream>>>(
      xb, HID, WinT, HID, xz, 2 * INNER, HID, 0);

  // 2. xc = silu(causal_depthwise_conv(xi) + conv_b)  (+ bf16 copy)
  conv_silu_kernel<<<(S_LEN * INNER + 255) / 256, 256, 0, stream>>>(
      xz, conv_w, conv_b, xc, xcb);

  // 3. xp = xc @ W_x   (M=2048, N=96, K=2048)  [bf16 MFMA, 8-way K-split]
  gemm_bf16<<<dim3(1, 2048 / 128, XPSPLIT), 256, 0, stream>>>(
      xcb, INNER, WxT, INNER, xpPart, XPAD, INNER / XPSPLIT,
      (size_t)S_LEN * XPAD);
  reduce_xp_kernel<<<(S_LEN * (XPW / 4) + 255) / 256, 256, 0, stream>>>(
      xpPart, xp);

  // 4. delta = softplus(xp[:, :64] @ W_delta + b_delta)
  gemm_tiled<1><<<dim3(2048 / 64, 2048 / 64), 256, 0, stream>>>(
      xp, XPW, W_delta, INNER, delta, INNER, S_LEN, INNER, DRANK, b_delta);

  // 5. chunk-parallel SSM scan -> ybf (fused +xc*D, *silu(z), bf16 cast)
  scan_pass1<<<dim3(NCHUNK, INNER / 256), 256, 0, stream>>>(
      delta, xp, xc, A_log, Aprod, Hend);
  scan_pass2<<<(INNER * LSTATE) / 256, 256, 0, stream>>>(Aprod, Hend, Hin);
  scan_pass3<<<dim3(NCHUNK, INNER / 256), 256, 0, stream>>>(
      delta, xp, xc, xz, A_log, Dvec, Hin, ybf);

  // 6. out = y @ W_out  (M=2048, N=1024, K=2048)  [bf16 MFMA, 2-way K-split]
  gemm_bf16<<<dim3(1024 / 128, 2048 / 128, 2), 256, 0, stream>>>(
      ybf, INNER, WoutT, INNER, outPart, HID, INNER / 2,
      (size_t)S_LEN * HID);
  reduce_out_kernel<<<(S_LEN * (HID / 4) + 255) / 256, 256, 0, stream>>>(
      outPart, out);
}